// Round 9
// baseline (329.637 us; speedup 1.0000x reference)
//
#include <hip/hip_runtime.h>

typedef __bf16 bf16;
typedef __bf16 bf16x4 __attribute__((ext_vector_type(4)));
typedef __bf16 bf16x8 __attribute__((ext_vector_type(8)));
typedef float  f32x4  __attribute__((ext_vector_type(4)));

// Problem constants
#define NB    16384      // batch
#define NOBS  568
#define NH    256
#define NAG   19         // N_OTHER

// ws byte offsets (all 16B aligned). ALL weights CHUNK-MAJOR [K/32][256][32].
#define OFF_WT_MU    0u          // [18][256][32]
#define OFF_WT_VAR   294912u     // [18][256][32]
#define OFF_WT_SELF  589824u     // [2][256][32]
#define OFF_WT_OTHER 622592u     // [1][256][32]
#define OFF_WT_Q     638976u     // [8][256][32] (chunk-8 overflow -> WT_K)
#define OFF_WT_K     770048u     // [8][256][32] (chunk-8 overflow -> V1)
#define OFF_WT_V1    901120u     // [8][256][32] (chunk-8 overflow -> V2)
#define OFF_WT_V2    1032192u    // [8][256][32] (chunk-8 overflow -> A1)
#define OFF_WT_A1    1163264u    // [8][256][32]
#define OFF_WT_A2    1294336u    // [8][256][32]
#define OFF_Z        1425408u    // [16384][256] bf16
#define OFF_SELF     9814016u
#define OFF_Q        18202624u
#define OFF_SV       26591232u
#define OFF_H        34979840u

static __device__ __forceinline__ unsigned short bfbits(float v) {
  bf16 b = (bf16)v;
  union { bf16 b; unsigned short u; } cvt; cvt.b = b; return cvt.u;
}

// async global->LDS, 16B per lane; dest = wave-uniform base + lane*16
static __device__ __forceinline__ void gload16(const bf16* g, bf16* l) {
  __builtin_amdgcn_global_load_lds(
      (const __attribute__((address_space(1))) void*)g,
      (__attribute__((address_space(3))) void*)(void*)l, 16, 0, 0);
}

// ---------------------------------------------------------------------------
// Weight prep (round-18 version: chunk-major, coalesced reads; unchanged).
// ---------------------------------------------------------------------------
__global__ __launch_bounds__(256) void wprep(
    const float* __restrict__ Wmu, const float* __restrict__ Wvar,
    const float* __restrict__ Wself, const float* __restrict__ Wother,
    const float* __restrict__ Wq, const float* __restrict__ Wk,
    const float* __restrict__ Wv, const float* __restrict__ Wa, char* wsb)
{
  const float* src; bf16* dst; int K, Kp;
  switch (blockIdx.y) {
    case 0: src = Wmu;        dst = (bf16*)(wsb + OFF_WT_MU);    K = 568; Kp = 576; break;
    case 1: src = Wvar;       dst = (bf16*)(wsb + OFF_WT_VAR);   K = 568; Kp = 576; break;
    case 2: src = Wself;      dst = (bf16*)(wsb + OFF_WT_SELF);  K = 36;  Kp = 64;  break;
    case 3: src = Wother;     dst = (bf16*)(wsb + OFF_WT_OTHER); K = 28;  Kp = 32;  break;
    case 4: src = Wq;         dst = (bf16*)(wsb + OFF_WT_Q);     K = 256; Kp = 256; break;
    case 5: src = Wk;         dst = (bf16*)(wsb + OFF_WT_K);     K = 256; Kp = 256; break;
    case 6: src = Wv;         dst = (bf16*)(wsb + OFF_WT_V1);    K = 256; Kp = 256; break;
    case 7: src = Wv + 65536; dst = (bf16*)(wsb + OFF_WT_V2);    K = 256; Kp = 256; break;
    case 8: src = Wa;         dst = (bf16*)(wsb + OFF_WT_A1);    K = 256; Kp = 256; break;
    default: src = Wa + 65536; dst = (bf16*)(wsb + OFF_WT_A2);   K = 256; Kp = 256; break;
  }
  int total = 256 * Kp;
  for (int i = blockIdx.x * 256 + threadIdx.x; i < total; i += gridDim.x * 256) {
    int n = i & 255, kk = (i >> 8) & 31, ch = i >> 13;
    int k = ch * 32 + kk;
    dst[ch * 8192 + n * 32 + kk] = (k < K) ? (bf16)src[k * 256 + n] : (bf16)0.f;
  }
}

// ---------------------------------------------------------------------------
// z + self GEMM (round-18 async-B version, unchanged; proven).
// ---------------------------------------------------------------------------
__global__ __launch_bounds__(256, 3) void gemm_zself(
    const float* __restrict__ x,
    const bf16* __restrict__ WtMuC, const bf16* __restrict__ WtVarC,
    const bf16* __restrict__ WtSelfC,
    const float* __restrict__ b_mu, const float* __restrict__ b_var,
    const float* __restrict__ b_self, const float* __restrict__ eps,
    bf16* __restrict__ zout, bf16* __restrict__ selfout)
{
  __shared__ bf16 lA[2][64 * 40];                  // 10240 B (padded, ds_write)
  __shared__ __align__(16) bf16 lB1[2][128 * 32];  // 16384 B (gload)
  __shared__ __align__(16) bf16 lB2[2][128 * 32];  // 16384 B (gload, z only)

  const int tid = threadIdx.x;
  const int wave = tid >> 6;
  const int lane = tid & 63;
  const int quad = lane >> 4;
  const int m = lane & 15;
  const int rowbase = blockIdx.x * 64;
  const int colbase = (blockIdx.y & 1) * 128;
  const bool isZ = blockIdx.y < 2;
  const int nch = isZ ? 18 : 2;                    // K = 576 or 64
  const bf16* __restrict__ W1 = isZ ? WtMuC : WtSelfC;
  const float* __restrict__ bias = isZ ? b_mu : b_self;

  f32x4 acc[8], accB[8];
  const f32x4 z4 = {0.f, 0.f, 0.f, 0.f};
#pragma unroll
  for (int ct = 0; ct < 8; ++ct) { acc[ct] = z4; accB[ct] = z4; }

  const int ar0 = tid >> 3, afs0 = tid & 7;
  const int ar1 = (tid + 256) >> 3, afs1 = (tid + 256) & 7;

  auto loadA = [&](int kc, int fs, int r, float4& f) {
    int k = kc + fs * 4;
    const float* src = x + (size_t)(rowbase + r) * 568 + k;
    if (k + 4 <= 568) {
      f = *(const float4*)src;
    } else {
      f.x = (k + 0 < 568) ? src[0] : 0.f;
      f.y = (k + 1 < 568) ? src[1] : 0.f;
      f.z = (k + 2 < 568) ? src[2] : 0.f;
      f.w = (k + 3 < 568) ? src[3] : 0.f;
    }
  };
  auto writeA = [&](int buf, int fs, int r, const float4& f) {
    bf16x4 o = {(bf16)f.x, (bf16)f.y, (bf16)f.z, (bf16)f.w};
    *(bf16x4*)(&lA[buf][r * 40 + fs * 4]) = o;
  };
  auto stageB = [&](int buf, int ch) {
    const bf16* s1 = W1 + (size_t)ch * 8192 + colbase * 32 + tid * 8;
    gload16(s1, &lB1[buf][wave * 512]);
    gload16(s1 + 2048, &lB1[buf][2048 + wave * 512]);
    if (isZ) {
      const bf16* s2 = WtVarC + (size_t)ch * 8192 + colbase * 32 + tid * 8;
      gload16(s2, &lB2[buf][wave * 512]);
      gload16(s2 + 2048, &lB2[buf][2048 + wave * 512]);
    }
  };

  {
    float4 f0, f1;
    loadA(0, afs0, ar0, f0);
    loadA(0, afs1, ar1, f1);
    stageB(0, 0);
    writeA(0, afs0, ar0, f0);
    writeA(0, afs1, ar1, f1);
  }
  __syncthreads();

  for (int ch = 0; ch < nch; ++ch) {
    const int cur = ch & 1, nxt = cur ^ 1;
    float4 f0, f1;
    const bool more = (ch + 1 < nch);
    if (more) {
      stageB(nxt, ch + 1);
      loadA((ch + 1) * 32, afs0, ar0, f0);
      loadA((ch + 1) * 32, afs1, ar1, f1);
    }
    bf16x8 afrag = *(const bf16x8*)(&lA[cur][(wave * 16 + m) * 40 + quad * 8]);
#pragma unroll
    for (int ct = 0; ct < 8; ++ct) {
      bf16x8 bfrag = *(const bf16x8*)(&lB1[cur][(ct * 16 + m) * 32 + quad * 8]);
      acc[ct] = __builtin_amdgcn_mfma_f32_16x16x32_bf16(afrag, bfrag, acc[ct], 0, 0, 0);
      if (isZ) {
        bf16x8 b2 = *(const bf16x8*)(&lB2[cur][(ct * 16 + m) * 32 + quad * 8]);
        accB[ct] = __builtin_amdgcn_mfma_f32_16x16x32_bf16(afrag, b2, accB[ct], 0, 0, 0);
      }
    }
    if (more) {
      writeA(nxt, afs0, ar0, f0);
      writeA(nxt, afs1, ar1, f1);
    }
    __syncthreads();
  }

#pragma unroll
  for (int ct = 0; ct < 8; ++ct) {
    const int col = colbase + ct * 16 + m;
    const float bv = bias[col];
#pragma unroll
    for (int r = 0; r < 4; ++r) {
      const size_t row = (size_t)rowbase + wave * 16 + quad * 4 + r;
      float v = acc[ct][r] + bv;
      if (isZ) {
        float lv = accB[ct][r] + b_var[col];
        float zz = eps[row * 256 + col] * __expf(0.5f * lv) + v;
        zout[row * 256 + col] = (bf16)zz;
      } else {
        selfout[row * 256 + col] = (bf16)(v > 0.f ? v : 0.f);
      }
    }
  }
}

// ---------------------------------------------------------------------------
// ROUND-19: q + sv GEMM at 128x128 tiles (was 64x128). 2 rtiles x 8 ctiles
// per wave (acc 64 VGPRs); 16 MFMAs per {4 gloads + 1 barrier} step -- halves
// the barrier/staging overhead per output element. Same K-chunk order ->
// bit-identical outputs. LDS 32 KB -> 4 blocks/CU.
// ---------------------------------------------------------------------------
__global__ __launch_bounds__(256, 4) void gemm_qsv(
    const bf16* __restrict__ zb, const bf16* __restrict__ selfb,
    const bf16* __restrict__ WtQc, const bf16* __restrict__ WtV2c,
    const float* __restrict__ b_q, const float* __restrict__ b_v,
    bf16* __restrict__ qout, bf16* __restrict__ svout)
{
  __shared__ __align__(16) bf16 lA[2][128 * 32];
  __shared__ __align__(16) bf16 lB[2][128 * 32];

  const int tid = threadIdx.x;
  const int wave = tid >> 6;
  const int lane = tid & 63;
  const int quad = lane >> 4;
  const int m = lane & 15;
  const int rowbase = blockIdx.x * 128;
  const int colbase = (blockIdx.y & 1) * 128;
  const bool isQ = blockIdx.y < 2;
  const bf16* __restrict__ Ap = isQ ? zb : selfb;
  const bf16* __restrict__ Wc = isQ ? WtQc : WtV2c;
  const float* __restrict__ bias = isQ ? b_q : b_v;
  bf16* __restrict__ outp = isQ ? qout : svout;

  f32x4 acc[2][8];
  const f32x4 z4 = {0.f, 0.f, 0.f, 0.f};
#pragma unroll
  for (int rt = 0; rt < 2; ++rt)
#pragma unroll
    for (int ct = 0; ct < 8; ++ct) acc[rt][ct] = z4;

  const size_t arow0 = (size_t)(rowbase + (tid >> 2)) * 256 + (tid & 3) * 8;
  const size_t arow1 = arow0 + (size_t)64 * 256;
  const size_t bbase = (size_t)colbase * 32 + (size_t)tid * 8;

  auto stageQS = [&](int buf, int ch) {
    const size_t cof = (size_t)ch * 8192;
    gload16(Ap + arow0 + ch * 32, &lA[buf][wave * 512]);
    gload16(Ap + arow1 + ch * 32, &lA[buf][2048 + wave * 512]);
    gload16(Wc + cof + bbase, &lB[buf][wave * 512]);
    gload16(Wc + cof + bbase + 2048, &lB[buf][2048 + wave * 512]);
  };

  stageQS(0, 0);
  __syncthreads();

#pragma unroll
  for (int ch = 0; ch < 8; ++ch) {
    const int cur = ch & 1;
    if (ch < 7) stageQS(cur ^ 1, ch + 1);
#pragma unroll
    for (int rt = 0; rt < 2; ++rt) {
      bf16x8 afrag = *(const bf16x8*)(&lA[cur][(wave * 32 + rt * 16 + m) * 32 + quad * 8]);
#pragma unroll
      for (int ct = 0; ct < 8; ++ct) {
        bf16x8 bfrag = *(const bf16x8*)(&lB[cur][(ct * 16 + m) * 32 + quad * 8]);
        acc[rt][ct] = __builtin_amdgcn_mfma_f32_16x16x32_bf16(afrag, bfrag, acc[rt][ct], 0, 0, 0);
      }
    }
    __syncthreads();
  }

#pragma unroll
  for (int rt = 0; rt < 2; ++rt)
#pragma unroll
    for (int ct = 0; ct < 8; ++ct) {
      const int col = colbase + ct * 16 + m;
      const float bv = bias[col];
#pragma unroll
      for (int r = 0; r < 4; ++r) {
        const size_t row = (size_t)rowbase + wave * 32 + rt * 16 + quad * 4 + r;
        float v = acc[rt][ct][r] + bv;
        if (isQ) v = (v > 0.f ? v : 0.f);
        outp[row * 256 + col] = (bf16)v;
      }
    }
}

// ---------------------------------------------------------------------------
// ROUND-19: dual-A GEMM at 128x128 tiles (was 64x128); 16 unified K-steps.
// Same ordering -> bit-identical.
// ---------------------------------------------------------------------------
__global__ __launch_bounds__(256, 4) void gemm_dualA(
    const bf16* __restrict__ A1, const bf16* __restrict__ A2,
    const bf16* __restrict__ Wt1c, const bf16* __restrict__ Wt2c,
    const float* __restrict__ bias, float* __restrict__ outp)
{
  __shared__ __align__(16) bf16 lA[2][128 * 32];
  __shared__ __align__(16) bf16 lB[2][128 * 32];

  const int tid = threadIdx.x;
  const int wave = tid >> 6;
  const int lane = tid & 63;
  const int quad = lane >> 4;
  const int m = lane & 15;
  const int rowbase = blockIdx.x * 128;
  const int colbase = blockIdx.y * 128;

  f32x4 acc[2][8];
  const f32x4 z4 = {0.f, 0.f, 0.f, 0.f};
#pragma unroll
  for (int rt = 0; rt < 2; ++rt)
#pragma unroll
    for (int ct = 0; ct < 8; ++ct) acc[rt][ct] = z4;

  const size_t arow0 = (size_t)(rowbase + (tid >> 2)) * 256 + (tid & 3) * 8;
  const size_t arow1 = arow0 + (size_t)64 * 256;
  const size_t bbase = (size_t)colbase * 32 + (size_t)tid * 8;

  auto stageT = [&](int buf, int t) {
    const int ch = t & 7;
    const bf16* Astep = (t < 8) ? A1 : A2;
    const bf16* Wstep = (t < 8) ? Wt1c : Wt2c;
    const size_t cof = (size_t)ch * 8192;
    gload16(Astep + arow0 + ch * 32, &lA[buf][wave * 512]);
    gload16(Astep + arow1 + ch * 32, &lA[buf][2048 + wave * 512]);
    gload16(Wstep + cof + bbase, &lB[buf][wave * 512]);
    gload16(Wstep + cof + bbase + 2048, &lB[buf][2048 + wave * 512]);
  };

  stageT(0, 0);
  __syncthreads();

#pragma unroll
  for (int t = 0; t < 16; ++t) {
    const int cur = t & 1;
    if (t < 15) stageT(cur ^ 1, t + 1);
#pragma unroll
    for (int rt = 0; rt < 2; ++rt) {
      bf16x8 afrag = *(const bf16x8*)(&lA[cur][(wave * 32 + rt * 16 + m) * 32 + quad * 8]);
#pragma unroll
      for (int ct = 0; ct < 8; ++ct) {
        bf16x8 bfrag = *(const bf16x8*)(&lB[cur][(ct * 16 + m) * 32 + quad * 8]);
        acc[rt][ct] = __builtin_amdgcn_mfma_f32_16x16x32_bf16(afrag, bfrag, acc[rt][ct], 0, 0, 0);
      }
    }
    __syncthreads();
  }

#pragma unroll
  for (int rt = 0; rt < 2; ++rt)
#pragma unroll
    for (int ct = 0; ct < 8; ++ct) {
      const int col = colbase + ct * 16 + m;
      const float bv = bias[col];
#pragma unroll
      for (int r = 0; r < 4; ++r) {
        const size_t row = (size_t)rowbase + wave * 32 + rt * 16 + quad * 4 + r;
        float v = acc[rt][ct][r] + bv;
        outp[row * 256 + col] = (v > 0.f ? v : 0.f);
      }
    }
}

// ---------------------------------------------------------------------------
// Fused attention (round-3/5 version, proven ~158-160 us; unchanged).
// ---------------------------------------------------------------------------
__global__ __launch_bounds__(512, 4) void k_fused(
    const float* __restrict__ x, const bf16* __restrict__ qb,
    const bf16* __restrict__ svb,
    const bf16* __restrict__ WtOther, const float* __restrict__ b_other,
    const bf16* __restrict__ WtKc, const float* __restrict__ b_k,
    const bf16* __restrict__ WtVc,
    float* __restrict__ att_out, bf16* __restrict__ hb)
{
  __shared__ bf16 ldsO[80 * 264];     // 42240 B  other_em (16B-group stride 33)
  __shared__ bf16 ldsA1[80 * 40];     //  6400 B  agents tile; REUSED: spart/attl
  __shared__ bf16 qh16[1024];         //  2048 B  q (bf16); REUSED: h partials
  __shared__ bf16 svl16[1024];        //  2048 B  sv (bf16)
  float* spart = (float*)ldsA1;        // [0..320)  floats: 4 K-waves x 80 rows
  float* attl  = (float*)ldsA1 + 320;  // [320..400) floats: att weights, row order

  const int tid = threadIdx.x, wave = tid >> 6, lane = tid & 63;
  const int quad = lane >> 4, m = lane & 15;
  const int b0 = blockIdx.x * 4;
  const int kvw = wave & 3;            // column-group within K or V half
  const bool isV = wave >= 4;

  // ---- phase 0: stage q, sv (bf16 copies), agents_info (interleaved rows)
  ((unsigned*)qh16)[tid]  = ((const unsigned*)(qb  + (size_t)b0 * 256))[tid];
  ((unsigned*)svl16)[tid] = ((const unsigned*)(svb + (size_t)b0 * 256))[tid];
  for (int i = tid; i < 80 * 16; i += 512) {
    int r = i >> 4, kk = (i & 15) * 2;   // lds row r = agent*4 + batch
    int n = r >> 2, bb = r & 3;
    float v0 = 0.f, v1 = 0.f;
    if (n < 19) {
      const float* base = x + (size_t)(b0 + bb) * NOBS + 36 + n * 28;
      if (kk < 28) v0 = base[kk];
      if (kk + 1 < 28) v1 = base[kk + 1];
    }
    unsigned u0 = bfbits(v0), u1 = bfbits(v1);
    *(unsigned*)(ldsA1 + r * 40 + kk) = u0 | (u1 << 16);
  }

  const f32x4 z4 = {0.f, 0.f, 0.f, 0.f};

  // ---- issue first main-loop B buffer early (independent of all LDS)
  const bf16* __restrict__ Bc = isV ? WtVc : WtKc;
  const int cb = (kvw * 64 + m) * 32 + quad * 8;   // ((4*kvw+c)*16+m)*32+q*8 == cb+c*512
  bf16x8 bE[4];
#pragma unroll
  for (int c = 0; c < 4; ++c) bE[c] = *(const bf16x8*)(Bc + cb + c * 512);

  __syncthreads();

  // ---- phase 1: other_em = relu(A1 @ WtOther^T + b_other), K=32.
  {
    float bo[2];
    bf16x8 bfr[2];
#pragma unroll
    for (int c = 0; c < 2; ++c) {
      int col = (2 * wave + c) * 16 + m;
      bo[c] = b_other[col];
      bfr[c] = *(const bf16x8*)(WtOther + col * 32 + quad * 8);
    }
    f32x4 acc1[5][2];
#pragma unroll
    for (int rt = 0; rt < 5; ++rt) {
      bf16x8 a = *(const bf16x8*)(ldsA1 + (rt * 16 + m) * 40 + quad * 8);
#pragma unroll
      for (int c = 0; c < 2; ++c)
        acc1[rt][c] = __builtin_amdgcn_mfma_f32_16x16x32_bf16(a, bfr[c], z4, 0, 0, 0);
    }
#pragma unroll
    for (int rt = 0; rt < 5; ++rt)
#pragma unroll
      for (int c = 0; c < 2; ++c) {
        int col = (2 * wave + c) * 16 + m;
#pragma unroll
        for (int r = 0; r < 4; ++r) {
          float v = acc1[rt][c][r] + bo[c];
          v = v > 0.f ? v : 0.f;
          unsigned u = bfbits(v);
          unsigned other = (unsigned)__shfl_xor((int)u, 1, 64);
          if ((m & 1) == 0) {
            int rowl = rt * 16 + quad * 4 + r;
            *(unsigned*)(ldsO + rowl * 264 + col) = u | (other << 16);
          }
        }
      }
  }
  __syncthreads();   // ldsA1 (agents tile) dead from here; spart/attl overlay

  // ---- unified main GEMM: 80 rows x 512 cols ([WtK | WtV]), 8 chunks,
  // ping-pong software pipeline (prefetch distance 1, no conditionals).
  f32x4 acc[5][4];
#pragma unroll
  for (int rt = 0; rt < 5; ++rt)
#pragma unroll
    for (int c = 0; c < 4; ++c) acc[rt][c] = z4;

  {
#pragma unroll 1
    for (int ch = 0; ch < 8; ch += 2) {
      bf16x8 bO[4];
#pragma unroll
      for (int c = 0; c < 4; ++c)
        bO[c] = *(const bf16x8*)(Bc + (size_t)(ch + 1) * 8192 + cb + c * 512);
      const int kc0 = ch * 32;
#pragma unroll
      for (int rt = 0; rt < 5; ++rt) {
        bf16x8 a = *(const bf16x8*)(ldsO + (rt * 16 + m) * 264 + kc0 + quad * 8);
#pragma unroll
        for (int c = 0; c < 4; ++c)
          acc[rt][c] = __builtin_amdgcn_mfma_f32_16x16x32_bf16(a, bE[c], acc[rt][c], 0, 0, 0);
      }
      // prefetch ch+2; at ch==6 this reads chunk 8 = adjacent weight region
#pragma unroll
      for (int c = 0; c < 4; ++c)
        bE[c] = *(const bf16x8*)(Bc + (size_t)(ch + 2) * 8192 + cb + c * 512);
      const int kc1 = kc0 + 32;
#pragma unroll
      for (int rt = 0; rt < 5; ++rt) {
        bf16x8 a = *(const bf16x8*)(ldsO + (rt * 16 + m) * 264 + kc1 + quad * 8);
#pragma unroll
        for (int c = 0; c < 4; ++c)
          acc[rt][c] = __builtin_amdgcn_mfma_f32_16x16x32_bf16(a, bO[c], acc[rt][c], 0, 0, 0);
      }
    }
  }

  // ---- K-waves: scores = (relu(k)+b_k) . q, reduce over lanes -> spart
  if (!isV) {
    float qreg[4][4], bkreg[4];
#pragma unroll
    for (int c = 0; c < 4; ++c) {
      int col = (4 * wave + c) * 16 + m;
      bkreg[c] = b_k[col];
#pragma unroll
      for (int r = 0; r < 4; ++r) qreg[c][r] = (float)qh16[r * 256 + col];
    }
#pragma unroll
    for (int rt = 0; rt < 5; ++rt) {
      float part[4] = {0.f, 0.f, 0.f, 0.f};
#pragma unroll
      for (int c = 0; c < 4; ++c) {
#pragma unroll
        for (int r = 0; r < 4; ++r) {
          float kv = acc[rt][c][r] + bkreg[c];
          kv = kv > 0.f ? kv : 0.f;
          part[r] += kv * qreg[c][r];
        }
      }
#pragma unroll
      for (int r = 0; r < 4; ++r) {
        float p = part[r];
        p += __shfl_xor(p, 1, 64);
        p += __shfl_xor(p, 2, 64);
        p += __shfl_xor(p, 4, 64);
        p += __shfl_xor(p, 8, 64);
        if (m == 0) spart[wave * 80 + rt * 16 + quad * 4 + r] = p;
      }
    }
  }
  __syncthreads();

  // ---- softmax: wave w = batch w, lanes 0-18 = agents (width-32 tree)
  if (!isV && lane < 32) {
    const int bb = wave, j = lane;      // batch, agent
    float s = -1e30f;
    if (j < 19) {
      int row = j * 4 + bb;             // interleaved: row = agent*4 + batch
      s = (spart[row] + spart[80 + row] + spart[160 + row] + spart[240 + row]) * 0.0625f;
    }
    float mx = s;
#pragma unroll
    for (int off = 16; off >= 1; off >>= 1) mx = fmaxf(mx, __shfl_xor(mx, off, 32));
    float e = (j < 19) ? __expf(s - mx) : 0.f;
    float sum = e;
#pragma unroll
    for (int off = 16; off >= 1; off >>= 1) sum += __shfl_xor(sum, off, 32);
    float inv = 1.f / sum;
    float a = e * inv;
    if (j < 20) attl[j * 4 + bb] = a;   // j==19 writes the zero pad row
    if (j < 19) att_out[(size_t)(b0 + bb) * 19 + j] = a;
  }
  __syncthreads();

  // ---- V-waves: epilogue  h = sum_rows att * relu(v + sv)
  if (isV) {
    float svreg[4][4];
#pragma unroll
    for (int c = 0; c < 4; ++c) {
      int col = (4 * kvw + c) * 16 + m;
#pragma unroll
      for (int r = 0; r < 4; ++r) svreg[c][r] = (float)svl16[r * 256 + col];
    }
    float hacc[4][4];   // [c][batch==r]
#pragma unroll
    for (int c = 0; c < 4; ++c)
#pragma unroll
      for (int r = 0; r < 4; ++r) hacc[c][r] = 0.f;
#pragma unroll
    for (int rt = 0; rt < 5; ++rt) {
      float av[4];
#pragma unroll
      for (int r = 0; r < 4; ++r) av[r] = attl[rt * 16 + quad * 4 + r];
#pragma unroll
      for (int c = 0; c < 4; ++c) {
#pragma unroll
        for (int r = 0; r < 4; ++r) {
          float v = acc[rt][c][r] + svreg[c][r];
          v = v > 0.f ? v : 0.f;
          hacc[c][r] += v * av[r];
        }
      }
    }
#pragma unroll
    for (int c = 0; c < 4; ++c)
#pragma unroll
      for (int r = 0; r < 4; ++r) {
        float h = hacc[c][r];
        h += __shfl_xor(h, 16, 64);
        h += __shfl_xor(h, 32, 64);
        if (quad == 0) qh16[r * 256 + (4 * kvw + c) * 16 + m] = (bf16)h;
      }
  }
  __syncthreads();
  ((unsigned*)(hb + (size_t)b0 * 256))[tid] = ((const unsigned*)qh16)[tid];
}

// ---------------------------------------------------------------------------
extern "C" void kernel_launch(void* const* d_in, const int* in_sizes, int n_in,
                              void* d_out, int out_size, void* d_ws, size_t ws_size,
                              hipStream_t stream) {
  (void)in_sizes; (void)n_in; (void)out_size; (void)ws_size;
  const float* x      = (const float*)d_in[0];
  const float* eps    = (const float*)d_in[1];
  const float* W_mu   = (const float*)d_in[2];
  const float* b_mu   = (const float*)d_in[3];
  const float* W_var  = (const float*)d_in[4];
  const float* b_var  = (const float*)d_in[5];
  const float* W_self = (const float*)d_in[6];
  const float* b_self = (const float*)d_in[7];
  const float* W_other= (const float*)d_in[8];
  const float* b_other= (const float*)d_in[9];
  const float* W_q    = (const float*)d_in[10];
  const float* b_q    = (const float*)d_in[11];
  const float* W_k    = (const float*)d_in[12];
  const float* b_k    = (const float*)d_in[13];
  const float* W_v    = (const float*)d_in[14];
  const float* b_v    = (const float*)d_in[15];
  const float* W_a    = (const float*)d_in[16];
  const float* b_a    = (const float*)d_in[17];

  char* wsb = (char*)d_ws;
  bf16* WtMu    = (bf16*)(wsb + OFF_WT_MU);
  bf16* WtVar   = (bf16*)(wsb + OFF_WT_VAR);
  bf16* WtSelf  = (bf16*)(wsb + OFF_WT_SELF);
  bf16* WtOther = (bf16*)(wsb + OFF_WT_OTHER);
  bf16* WtQ     = (bf16*)(wsb + OFF_WT_Q);
  bf16* WtK     = (bf16*)(wsb + OFF_WT_K);
  bf16* WtV1    = (bf16*)(wsb + OFF_WT_V1);
  bf16* WtV2    = (bf16*)(wsb + OFF_WT_V2);
  bf16* WtA1    = (bf16*)(wsb + OFF_WT_A1);
  bf16* WtA2    = (bf16*)(wsb + OFF_WT_A2);
  bf16* zbuf    = (bf16*)(wsb + OFF_Z);
  bf16* selfbuf = (bf16*)(wsb + OFF_SELF);
  bf16* qbuf    = (bf16*)(wsb + OFF_Q);
  bf16* svbuf   = (bf16*)(wsb + OFF_SV);
  bf16* hbuf    = (bf16*)(wsb + OFF_H);

  float* out = (float*)d_out;
  float* att_out = out + (size_t)NB * 256;

  dim3 blk(256);
  wprep<<<dim3(160, 10), blk, 0, stream>>>(W_mu, W_var, W_self, W_other, W_q, W_k, W_v, W_a, wsb);
  // z = eps*exp(0.5*logvar)+mu  AND  self_em = relu(x@W_self+b), async-B staged
  gemm_zself<<<dim3(NB / 64, 4), blk, 0, stream>>>(x, WtMu, WtVar, WtSelf,
                                                   b_mu, b_var, b_self, eps, zbuf, selfbuf);
  // q = relu(z@W_q+b_q)  AND  sv = self_em@W_v[256:]+b_v  (128x128 tiles)
  gemm_qsv<<<dim3(NB / 128, 4), blk, 0, stream>>>(zbuf, selfbuf, WtQ, WtV2,
                                                  b_q, b_v, qbuf, svbuf);
  // fused: other_em -> [k | v] unified GEMM -> scores -> softmax -> h
  k_fused<<<NB / 4, dim3(512), 0, stream>>>(x, qbuf, svbuf, WtOther, b_other, WtK, b_k,
                                            WtV1, att_out, hbuf);
  // out = relu([h; self_em] @ W_a + b_a)   (dual-A, 128x128 tiles)
  gemm_dualA<<<dim3(NB / 128, 2), blk, 0, stream>>>(hbuf, selfbuf, WtA1, WtA2, b_a, out);
}

// Round 11
// 329.012 us; speedup vs baseline: 1.0019x; 1.0019x over previous
//
#include <hip/hip_runtime.h>

typedef __bf16 bf16;
typedef __bf16 bf16x4 __attribute__((ext_vector_type(4)));
typedef __bf16 bf16x8 __attribute__((ext_vector_type(8)));
typedef float  f32x4  __attribute__((ext_vector_type(4)));

// Problem constants
#define NB    16384      // batch
#define NOBS  568
#define NH    256
#define NAG   19         // N_OTHER

// ws byte offsets (all 16B aligned). ALL weights CHUNK-MAJOR [K/32][256][32].
#define OFF_WT_MU    0u          // [18][256][32]
#define OFF_WT_VAR   294912u     // [18][256][32]
#define OFF_WT_SELF  589824u     // [2][256][32]
#define OFF_WT_OTHER 622592u     // [1][256][32]
#define OFF_WT_Q     638976u     // [8][256][32] (chunk-8 overflow -> WT_K)
#define OFF_WT_K     770048u     // [8][256][32] (chunk-8 overflow -> V1)
#define OFF_WT_V1    901120u     // [8][256][32] (chunk-8 overflow -> V2)
#define OFF_WT_V2    1032192u    // [8][256][32] (chunk-8 overflow -> A1)
#define OFF_WT_A1    1163264u    // [8][256][32]
#define OFF_WT_A2    1294336u    // [8][256][32]
#define OFF_Z        1425408u    // [16384][256] bf16
#define OFF_SELF     9814016u
#define OFF_Q        18202624u
#define OFF_SV       26591232u
#define OFF_H        34979840u

static __device__ __forceinline__ unsigned short bfbits(float v) {
  bf16 b = (bf16)v;
  union { bf16 b; unsigned short u; } cvt; cvt.b = b; return cvt.u;
}

// async global->LDS, 16B per lane; dest = wave-uniform base + lane*16
static __device__ __forceinline__ void gload16(const bf16* g, bf16* l) {
  __builtin_amdgcn_global_load_lds(
      (const __attribute__((address_space(1))) void*)g,
      (__attribute__((address_space(3))) void*)(void*)l, 16, 0, 0);
}

// ---------------------------------------------------------------------------
// Weight prep (round-18 version: chunk-major, coalesced reads; unchanged).
// ---------------------------------------------------------------------------
__global__ __launch_bounds__(256) void wprep(
    const float* __restrict__ Wmu, const float* __restrict__ Wvar,
    const float* __restrict__ Wself, const float* __restrict__ Wother,
    const float* __restrict__ Wq, const float* __restrict__ Wk,
    const float* __restrict__ Wv, const float* __restrict__ Wa, char* wsb)
{
  const float* src; bf16* dst; int K, Kp;
  switch (blockIdx.y) {
    case 0: src = Wmu;        dst = (bf16*)(wsb + OFF_WT_MU);    K = 568; Kp = 576; break;
    case 1: src = Wvar;       dst = (bf16*)(wsb + OFF_WT_VAR);   K = 568; Kp = 576; break;
    case 2: src = Wself;      dst = (bf16*)(wsb + OFF_WT_SELF);  K = 36;  Kp = 64;  break;
    case 3: src = Wother;     dst = (bf16*)(wsb + OFF_WT_OTHER); K = 28;  Kp = 32;  break;
    case 4: src = Wq;         dst = (bf16*)(wsb + OFF_WT_Q);     K = 256; Kp = 256; break;
    case 5: src = Wk;         dst = (bf16*)(wsb + OFF_WT_K);     K = 256; Kp = 256; break;
    case 6: src = Wv;         dst = (bf16*)(wsb + OFF_WT_V1);    K = 256; Kp = 256; break;
    case 7: src = Wv + 65536; dst = (bf16*)(wsb + OFF_WT_V2);    K = 256; Kp = 256; break;
    case 8: src = Wa;         dst = (bf16*)(wsb + OFF_WT_A1);    K = 256; Kp = 256; break;
    default: src = Wa + 65536; dst = (bf16*)(wsb + OFF_WT_A2);   K = 256; Kp = 256; break;
  }
  int total = 256 * Kp;
  for (int i = blockIdx.x * 256 + threadIdx.x; i < total; i += gridDim.x * 256) {
    int n = i & 255, kk = (i >> 8) & 31, ch = i >> 13;
    int k = ch * 32 + kk;
    dst[ch * 8192 + n * 32 + kk] = (k < K) ? (bf16)src[k * 256 + n] : (bf16)0.f;
  }
}

// ---------------------------------------------------------------------------
// z + self GEMM (round-18 async-B version, unchanged; proven).
// ---------------------------------------------------------------------------
__global__ __launch_bounds__(256, 3) void gemm_zself(
    const float* __restrict__ x,
    const bf16* __restrict__ WtMuC, const bf16* __restrict__ WtVarC,
    const bf16* __restrict__ WtSelfC,
    const float* __restrict__ b_mu, const float* __restrict__ b_var,
    const float* __restrict__ b_self, const float* __restrict__ eps,
    bf16* __restrict__ zout, bf16* __restrict__ selfout)
{
  __shared__ bf16 lA[2][64 * 40];                  // 10240 B (padded, ds_write)
  __shared__ __align__(16) bf16 lB1[2][128 * 32];  // 16384 B (gload)
  __shared__ __align__(16) bf16 lB2[2][128 * 32];  // 16384 B (gload, z only)

  const int tid = threadIdx.x;
  const int wave = tid >> 6;
  const int lane = tid & 63;
  const int quad = lane >> 4;
  const int m = lane & 15;
  const int rowbase = blockIdx.x * 64;
  const int colbase = (blockIdx.y & 1) * 128;
  const bool isZ = blockIdx.y < 2;
  const int nch = isZ ? 18 : 2;                    // K = 576 or 64
  const bf16* __restrict__ W1 = isZ ? WtMuC : WtSelfC;
  const float* __restrict__ bias = isZ ? b_mu : b_self;

  f32x4 acc[8], accB[8];
  const f32x4 z4 = {0.f, 0.f, 0.f, 0.f};
#pragma unroll
  for (int ct = 0; ct < 8; ++ct) { acc[ct] = z4; accB[ct] = z4; }

  const int ar0 = tid >> 3, afs0 = tid & 7;
  const int ar1 = (tid + 256) >> 3, afs1 = (tid + 256) & 7;

  auto loadA = [&](int kc, int fs, int r, float4& f) {
    int k = kc + fs * 4;
    const float* src = x + (size_t)(rowbase + r) * 568 + k;
    if (k + 4 <= 568) {
      f = *(const float4*)src;
    } else {
      f.x = (k + 0 < 568) ? src[0] : 0.f;
      f.y = (k + 1 < 568) ? src[1] : 0.f;
      f.z = (k + 2 < 568) ? src[2] : 0.f;
      f.w = (k + 3 < 568) ? src[3] : 0.f;
    }
  };
  auto writeA = [&](int buf, int fs, int r, const float4& f) {
    bf16x4 o = {(bf16)f.x, (bf16)f.y, (bf16)f.z, (bf16)f.w};
    *(bf16x4*)(&lA[buf][r * 40 + fs * 4]) = o;
  };
  auto stageB = [&](int buf, int ch) {
    const bf16* s1 = W1 + (size_t)ch * 8192 + colbase * 32 + tid * 8;
    gload16(s1, &lB1[buf][wave * 512]);
    gload16(s1 + 2048, &lB1[buf][2048 + wave * 512]);
    if (isZ) {
      const bf16* s2 = WtVarC + (size_t)ch * 8192 + colbase * 32 + tid * 8;
      gload16(s2, &lB2[buf][wave * 512]);
      gload16(s2 + 2048, &lB2[buf][2048 + wave * 512]);
    }
  };

  {
    float4 f0, f1;
    loadA(0, afs0, ar0, f0);
    loadA(0, afs1, ar1, f1);
    stageB(0, 0);
    writeA(0, afs0, ar0, f0);
    writeA(0, afs1, ar1, f1);
  }
  __syncthreads();

  for (int ch = 0; ch < nch; ++ch) {
    const int cur = ch & 1, nxt = cur ^ 1;
    float4 f0, f1;
    const bool more = (ch + 1 < nch);
    if (more) {
      stageB(nxt, ch + 1);
      loadA((ch + 1) * 32, afs0, ar0, f0);
      loadA((ch + 1) * 32, afs1, ar1, f1);
    }
    bf16x8 afrag = *(const bf16x8*)(&lA[cur][(wave * 16 + m) * 40 + quad * 8]);
#pragma unroll
    for (int ct = 0; ct < 8; ++ct) {
      bf16x8 bfrag = *(const bf16x8*)(&lB1[cur][(ct * 16 + m) * 32 + quad * 8]);
      acc[ct] = __builtin_amdgcn_mfma_f32_16x16x32_bf16(afrag, bfrag, acc[ct], 0, 0, 0);
      if (isZ) {
        bf16x8 b2 = *(const bf16x8*)(&lB2[cur][(ct * 16 + m) * 32 + quad * 8]);
        accB[ct] = __builtin_amdgcn_mfma_f32_16x16x32_bf16(afrag, b2, accB[ct], 0, 0, 0);
      }
    }
    if (more) {
      writeA(nxt, afs0, ar0, f0);
      writeA(nxt, afs1, ar1, f1);
    }
    __syncthreads();
  }

#pragma unroll
  for (int ct = 0; ct < 8; ++ct) {
    const int col = colbase + ct * 16 + m;
    const float bv = bias[col];
#pragma unroll
    for (int r = 0; r < 4; ++r) {
      const size_t row = (size_t)rowbase + wave * 16 + quad * 4 + r;
      float v = acc[ct][r] + bv;
      if (isZ) {
        float lv = accB[ct][r] + b_var[col];
        float zz = eps[row * 256 + col] * __expf(0.5f * lv) + v;
        zout[row * 256 + col] = (bf16)zz;
      } else {
        selfout[row * 256 + col] = (bf16)(v > 0.f ? v : 0.f);
      }
    }
  }
}

// ---------------------------------------------------------------------------
// q + sv GEMM (round-15 async version, 64x128 tiles; proven best config).
// ---------------------------------------------------------------------------
__global__ __launch_bounds__(256, 4) void gemm_qsv(
    const bf16* __restrict__ zb, const bf16* __restrict__ selfb,
    const bf16* __restrict__ WtQc, const bf16* __restrict__ WtV2c,
    const float* __restrict__ b_q, const float* __restrict__ b_v,
    bf16* __restrict__ qout, bf16* __restrict__ svout)
{
  __shared__ __align__(16) bf16 lA[2][64 * 32];
  __shared__ __align__(16) bf16 lB[2][128 * 32];

  const int tid = threadIdx.x;
  const int wave = tid >> 6;
  const int lane = tid & 63;
  const int quad = lane >> 4;
  const int m = lane & 15;
  const int rowbase = blockIdx.x * 64;
  const int colbase = (blockIdx.y & 1) * 128;
  const bool isQ = blockIdx.y < 2;
  const bf16* __restrict__ Ap = isQ ? zb : selfb;
  const bf16* __restrict__ Wc = isQ ? WtQc : WtV2c;
  const float* __restrict__ bias = isQ ? b_q : b_v;
  bf16* __restrict__ outp = isQ ? qout : svout;

  f32x4 acc[8];
  const f32x4 z4 = {0.f, 0.f, 0.f, 0.f};
#pragma unroll
  for (int ct = 0; ct < 8; ++ct) acc[ct] = z4;

  const size_t arow = (size_t)(rowbase + (tid >> 2)) * 256 + (tid & 3) * 8;
  const size_t bbase = (size_t)colbase * 32 + (size_t)tid * 8;

  gload16(Ap + arow, &lA[0][wave * 512]);
  gload16(Wc + bbase, &lB[0][wave * 512]);
  gload16(Wc + bbase + 2048, &lB[0][2048 + wave * 512]);
  __syncthreads();

#pragma unroll
  for (int ch = 0; ch < 8; ++ch) {
    const int cur = ch & 1;
    if (ch < 7) {
      const int nxt = cur ^ 1;
      const size_t cof = (size_t)(ch + 1) * 8192;
      gload16(Ap + arow + (ch + 1) * 32, &lA[nxt][wave * 512]);
      gload16(Wc + cof + bbase, &lB[nxt][wave * 512]);
      gload16(Wc + cof + bbase + 2048, &lB[nxt][2048 + wave * 512]);
    }
    bf16x8 afrag = *(const bf16x8*)(&lA[cur][(wave * 16 + m) * 32 + quad * 8]);
#pragma unroll
    for (int ct = 0; ct < 8; ++ct) {
      bf16x8 bfrag = *(const bf16x8*)(&lB[cur][(ct * 16 + m) * 32 + quad * 8]);
      acc[ct] = __builtin_amdgcn_mfma_f32_16x16x32_bf16(afrag, bfrag, acc[ct], 0, 0, 0);
    }
    __syncthreads();
  }

#pragma unroll
  for (int ct = 0; ct < 8; ++ct) {
    const int col = colbase + ct * 16 + m;
    const float bv = bias[col];
#pragma unroll
    for (int r = 0; r < 4; ++r) {
      const size_t row = (size_t)rowbase + wave * 16 + quad * 4 + r;
      float v = acc[ct][r] + bv;
      if (isQ) v = (v > 0.f ? v : 0.f);
      outp[row * 256 + col] = (bf16)v;
    }
  }
}

// ---------------------------------------------------------------------------
// dual-A GEMM (round-15 async version, 64x128 tiles; proven best config).
// ---------------------------------------------------------------------------
__global__ __launch_bounds__(256, 4) void gemm_dualA(
    const bf16* __restrict__ A1, const bf16* __restrict__ A2,
    const bf16* __restrict__ Wt1c, const bf16* __restrict__ Wt2c,
    const float* __restrict__ bias, float* __restrict__ outp)
{
  __shared__ __align__(16) bf16 lA[2][64 * 32];
  __shared__ __align__(16) bf16 lB[2][128 * 32];

  const int tid = threadIdx.x;
  const int wave = tid >> 6;
  const int lane = tid & 63;
  const int quad = lane >> 4;
  const int m = lane & 15;
  const int rowbase = blockIdx.x * 64;
  const int colbase = blockIdx.y * 128;

  f32x4 acc[8];
  const f32x4 z4 = {0.f, 0.f, 0.f, 0.f};
#pragma unroll
  for (int ct = 0; ct < 8; ++ct) acc[ct] = z4;

  const size_t arow = (size_t)(rowbase + (tid >> 2)) * 256 + (tid & 3) * 8;
  const size_t bbase = (size_t)colbase * 32 + (size_t)tid * 8;

  auto stageT = [&](int buf, int t) {
    const int ch = t & 7;
    const bf16* Astep = (t < 8) ? A1 : A2;
    const bf16* Wstep = (t < 8) ? Wt1c : Wt2c;
    const size_t cof = (size_t)ch * 8192;
    gload16(Astep + arow + ch * 32, &lA[buf][wave * 512]);
    gload16(Wstep + cof + bbase, &lB[buf][wave * 512]);
    gload16(Wstep + cof + bbase + 2048, &lB[buf][2048 + wave * 512]);
  };

  stageT(0, 0);
  __syncthreads();

#pragma unroll
  for (int t = 0; t < 16; ++t) {
    const int cur = t & 1;
    if (t < 15) stageT(cur ^ 1, t + 1);
    bf16x8 afrag = *(const bf16x8*)(&lA[cur][(wave * 16 + m) * 32 + quad * 8]);
#pragma unroll
    for (int ct = 0; ct < 8; ++ct) {
      bf16x8 bfrag = *(const bf16x8*)(&lB[cur][(ct * 16 + m) * 32 + quad * 8]);
      acc[ct] = __builtin_amdgcn_mfma_f32_16x16x32_bf16(afrag, bfrag, acc[ct], 0, 0, 0);
    }
    __syncthreads();
  }

#pragma unroll
  for (int ct = 0; ct < 8; ++ct) {
    const int col = colbase + ct * 16 + m;
    const float bv = bias[col];
#pragma unroll
    for (int r = 0; r < 4; ++r) {
      const size_t row = (size_t)rowbase + wave * 16 + quad * 4 + r;
      float v = acc[ct][r] + bv;
      outp[row * 256 + col] = (v > 0.f ? v : 0.f);
    }
  }
}

// ---------------------------------------------------------------------------
// Fused attention -- ROUND-20/21 CHANGE (only one): s_setprio(1)/(0) wrapped
// around the MFMA clusters (phase 1 + both halves of the ping-pong main
// loop). T5 regime check: this kernel has co-resident blocks at different
// phases and a K/V wave role split (attn-like, m191 +4-7%), not the
// lockstep single-GEMM case (m190 null). Everything else byte-identical
// to the proven round-8 version (158-161 us).
// ---------------------------------------------------------------------------
__global__ __launch_bounds__(512, 4) void k_fused(
    const float* __restrict__ x, const bf16* __restrict__ qb,
    const bf16* __restrict__ svb,
    const bf16* __restrict__ WtOther, const float* __restrict__ b_other,
    const bf16* __restrict__ WtKc, const float* __restrict__ b_k,
    const bf16* __restrict__ WtVc,
    float* __restrict__ att_out, bf16* __restrict__ hb)
{
  __shared__ bf16 ldsO[80 * 264];     // 42240 B  other_em (16B-group stride 33)
  __shared__ bf16 ldsA1[80 * 40];     //  6400 B  agents tile; REUSED: spart/attl
  __shared__ bf16 qh16[1024];         //  2048 B  q (bf16); REUSED: h partials
  __shared__ bf16 svl16[1024];        //  2048 B  sv (bf16)
  float* spart = (float*)ldsA1;        // [0..320)  floats: 4 K-waves x 80 rows
  float* attl  = (float*)ldsA1 + 320;  // [320..400) floats: att weights, row order

  const int tid = threadIdx.x, wave = tid >> 6, lane = tid & 63;
  const int quad = lane >> 4, m = lane & 15;
  const int b0 = blockIdx.x * 4;
  const int kvw = wave & 3;            // column-group within K or V half
  const bool isV = wave >= 4;

  // ---- phase 0: stage q, sv (bf16 copies), agents_info (interleaved rows)
  ((unsigned*)qh16)[tid]  = ((const unsigned*)(qb  + (size_t)b0 * 256))[tid];
  ((unsigned*)svl16)[tid] = ((const unsigned*)(svb + (size_t)b0 * 256))[tid];
  for (int i = tid; i < 80 * 16; i += 512) {
    int r = i >> 4, kk = (i & 15) * 2;   // lds row r = agent*4 + batch
    int n = r >> 2, bb = r & 3;
    float v0 = 0.f, v1 = 0.f;
    if (n < 19) {
      const float* base = x + (size_t)(b0 + bb) * NOBS + 36 + n * 28;
      if (kk < 28) v0 = base[kk];
      if (kk + 1 < 28) v1 = base[kk + 1];
    }
    unsigned u0 = bfbits(v0), u1 = bfbits(v1);
    *(unsigned*)(ldsA1 + r * 40 + kk) = u0 | (u1 << 16);
  }

  const f32x4 z4 = {0.f, 0.f, 0.f, 0.f};

  // ---- issue first main-loop B buffer early (independent of all LDS)
  const bf16* __restrict__ Bc = isV ? WtVc : WtKc;
  const int cb = (kvw * 64 + m) * 32 + quad * 8;   // ((4*kvw+c)*16+m)*32+q*8 == cb+c*512
  bf16x8 bE[4];
#pragma unroll
  for (int c = 0; c < 4; ++c) bE[c] = *(const bf16x8*)(Bc + cb + c * 512);

  __syncthreads();

  // ---- phase 1: other_em = relu(A1 @ WtOther^T + b_other), K=32.
  {
    float bo[2];
    bf16x8 bfr[2];
#pragma unroll
    for (int c = 0; c < 2; ++c) {
      int col = (2 * wave + c) * 16 + m;
      bo[c] = b_other[col];
      bfr[c] = *(const bf16x8*)(WtOther + col * 32 + quad * 8);
    }
    f32x4 acc1[5][2];
    __builtin_amdgcn_s_setprio(1);
#pragma unroll
    for (int rt = 0; rt < 5; ++rt) {
      bf16x8 a = *(const bf16x8*)(ldsA1 + (rt * 16 + m) * 40 + quad * 8);
#pragma unroll
      for (int c = 0; c < 2; ++c)
        acc1[rt][c] = __builtin_amdgcn_mfma_f32_16x16x32_bf16(a, bfr[c], z4, 0, 0, 0);
    }
    __builtin_amdgcn_s_setprio(0);
#pragma unroll
    for (int rt = 0; rt < 5; ++rt)
#pragma unroll
      for (int c = 0; c < 2; ++c) {
        int col = (2 * wave + c) * 16 + m;
#pragma unroll
        for (int r = 0; r < 4; ++r) {
          float v = acc1[rt][c][r] + bo[c];
          v = v > 0.f ? v : 0.f;
          unsigned u = bfbits(v);
          unsigned other = (unsigned)__shfl_xor((int)u, 1, 64);
          if ((m & 1) == 0) {
            int rowl = rt * 16 + quad * 4 + r;
            *(unsigned*)(ldsO + rowl * 264 + col) = u | (other << 16);
          }
        }
      }
  }
  __syncthreads();   // ldsA1 (agents tile) dead from here; spart/attl overlay

  // ---- unified main GEMM: 80 rows x 512 cols ([WtK | WtV]), 8 chunks,
  // ping-pong software pipeline (prefetch distance 1, no conditionals).
  f32x4 acc[5][4];
#pragma unroll
  for (int rt = 0; rt < 5; ++rt)
#pragma unroll
    for (int c = 0; c < 4; ++c) acc[rt][c] = z4;

  {
#pragma unroll 1
    for (int ch = 0; ch < 8; ch += 2) {
      bf16x8 bO[4];
#pragma unroll
      for (int c = 0; c < 4; ++c)
        bO[c] = *(const bf16x8*)(Bc + (size_t)(ch + 1) * 8192 + cb + c * 512);
      const int kc0 = ch * 32;
      __builtin_amdgcn_s_setprio(1);
#pragma unroll
      for (int rt = 0; rt < 5; ++rt) {
        bf16x8 a = *(const bf16x8*)(ldsO + (rt * 16 + m) * 264 + kc0 + quad * 8);
#pragma unroll
        for (int c = 0; c < 4; ++c)
          acc[rt][c] = __builtin_amdgcn_mfma_f32_16x16x32_bf16(a, bE[c], acc[rt][c], 0, 0, 0);
      }
      __builtin_amdgcn_s_setprio(0);
      // prefetch ch+2; at ch==6 this reads chunk 8 = adjacent weight region
#pragma unroll
      for (int c = 0; c < 4; ++c)
        bE[c] = *(const bf16x8*)(Bc + (size_t)(ch + 2) * 8192 + cb + c * 512);
      const int kc1 = kc0 + 32;
      __builtin_amdgcn_s_setprio(1);
#pragma unroll
      for (int rt = 0; rt < 5; ++rt) {
        bf16x8 a = *(const bf16x8*)(ldsO + (rt * 16 + m) * 264 + kc1 + quad * 8);
#pragma unroll
        for (int c = 0; c < 4; ++c)
          acc[rt][c] = __builtin_amdgcn_mfma_f32_16x16x32_bf16(a, bO[c], acc[rt][c], 0, 0, 0);
      }
      __builtin_amdgcn_s_setprio(0);
    }
  }

  // ---- K-waves: scores = (relu(k)+b_k) . q, reduce over lanes -> spart
  if (!isV) {
    float qreg[4][4], bkreg[4];
#pragma unroll
    for (int c = 0; c < 4; ++c) {
      int col = (4 * wave + c) * 16 + m;
      bkreg[c] = b_k[col];
#pragma unroll
      for (int r = 0; r < 4; ++r) qreg[c][r] = (float)qh16[r * 256 + col];
    }
#pragma unroll
    for (int rt = 0; rt < 5; ++rt) {
      float part[4] = {0.f, 0.f, 0.f, 0.f};
#pragma unroll
      for (int c = 0; c < 4; ++c) {
#pragma unroll
        for (int r = 0; r < 4; ++r) {
          float kv = acc[rt][c][r] + bkreg[c];
          kv = kv > 0.f ? kv : 0.f;
          part[r] += kv * qreg[c][r];
        }
      }
#pragma unroll
      for (int r = 0; r < 4; ++r) {
        float p = part[r];
        p += __shfl_xor(p, 1, 64);
        p += __shfl_xor(p, 2, 64);
        p += __shfl_xor(p, 4, 64);
        p += __shfl_xor(p, 8, 64);
        if (m == 0) spart[wave * 80 + rt * 16 + quad * 4 + r] = p;
      }
    }
  }
  __syncthreads();

  // ---- softmax: wave w = batch w, lanes 0-18 = agents (width-32 tree)
  if (!isV && lane < 32) {
    const int bb = wave, j = lane;      // batch, agent
    float s = -1e30f;
    if (j < 19) {
      int row = j * 4 + bb;             // interleaved: row = agent*4 + batch
      s = (spart[row] + spart[80 + row] + spart[160 + row] + spart[240 + row]) * 0.0625f;
    }
    float mx = s;
#pragma unroll
    for (int off = 16; off >= 1; off >>= 1) mx = fmaxf(mx, __shfl_xor(mx, off, 32));
    float e = (j < 19) ? __expf(s - mx) : 0.f;
    float sum = e;
#pragma unroll
    for (int off = 16; off >= 1; off >>= 1) sum += __shfl_xor(sum, off, 32);
    float inv = 1.f / sum;
    float a = e * inv;
    if (j < 20) attl[j * 4 + bb] = a;   // j==19 writes the zero pad row
    if (j < 19) att_out[(size_t)(b0 + bb) * 19 + j] = a;
  }
  __syncthreads();

  // ---- V-waves: epilogue  h = sum_rows att * relu(v + sv)
  if (isV) {
    float svreg[4][4];
#pragma unroll
    for (int c = 0; c < 4; ++c) {
      int col = (4 * kvw + c) * 16 + m;
#pragma unroll
      for (int r = 0; r < 4; ++r) svreg[c][r] = (float)svl16[r * 256 + col];
    }
    float hacc[4][4];   // [c][batch==r]
#pragma unroll
    for (int c = 0; c < 4; ++c)
#pragma unroll
      for (int r = 0; r < 4; ++r) hacc[c][r] = 0.f;
#pragma unroll
    for (int rt = 0; rt < 5; ++rt) {
      float av[4];
#pragma unroll
      for (int r = 0; r < 4; ++r) av[r] = attl[rt * 16 + quad * 4 + r];
#pragma unroll
      for (int c = 0; c < 4; ++c) {
#pragma unroll
        for (int r = 0; r < 4; ++r) {
          float v = acc[rt][c][r] + svreg[c][r];
          v = v > 0.f ? v : 0.f;
          hacc[c][r] += v * av[r];
        }
      }
    }
#pragma unroll
    for (int c = 0; c < 4; ++c)
#pragma unroll
      for (int r = 0; r < 4; ++r) {
        float h = hacc[c][r];
        h += __shfl_xor(h, 16, 64);
        h += __shfl_xor(h, 32, 64);
        if (quad == 0) qh16[r * 256 + (4 * kvw + c) * 16 + m] = (bf16)h;
      }
  }
  __syncthreads();
  ((unsigned*)(hb + (size_t)b0 * 256))[tid] = ((const unsigned*)qh16)[tid];
}

// ---------------------------------------------------------------------------
extern "C" void kernel_launch(void* const* d_in, const int* in_sizes, int n_in,
                              void* d_out, int out_size, void* d_ws, size_t ws_size,
                              hipStream_t stream) {
  (void)in_sizes; (void)n_in; (void)out_size; (void)ws_size;
  const float* x      = (const float*)d_in[0];
  const float* eps    = (const float*)d_in[1];
  const float* W_mu   = (const float*)d_in[2];
  const float* b_mu   = (const float*)d_in[3];
  const float* W_var  = (const float*)d_in[4];
  const float* b_var  = (const float*)d_in[5];
  const float* W_self = (const float*)d_in[6];
  const float* b_self = (const float*)d_in[7];
  const float* W_other= (const float*)d_in[8];
  const float* b_other= (const float*)d_in[9];
  const float* W_q    = (const float*)d_in[10];
  const float* b_q    = (const float*)d_in[11];
  const float* W_k    = (const float*)d_in[12];
  const float* b_k    = (const float*)d_in[13];
  const float* W_v    = (const float*)d_in[14];
  const float* b_v    = (const float*)d_in[15];
  const float* W_a    = (const float*)d_in[16];
  const float* b_a    = (const float*)d_in[17];

  char* wsb = (char*)d_ws;
  bf16* WtMu    = (bf16*)(wsb + OFF_WT_MU);
  bf16* WtVar   = (bf16*)(wsb + OFF_WT_VAR);
  bf16* WtSelf  = (bf16*)(wsb + OFF_WT_SELF);
  bf16* WtOther = (bf16*)(wsb + OFF_WT_OTHER);
  bf16* WtQ     = (bf16*)(wsb + OFF_WT_Q);
  bf16* WtK     = (bf16*)(wsb + OFF_WT_K);
  bf16* WtV1    = (bf16*)(wsb + OFF_WT_V1);
  bf16* WtV2    = (bf16*)(wsb + OFF_WT_V2);
  bf16* WtA1    = (bf16*)(wsb + OFF_WT_A1);
  bf16* WtA2    = (bf16*)(wsb + OFF_WT_A2);
  bf16* zbuf    = (bf16*)(wsb + OFF_Z);
  bf16* selfbuf = (bf16*)(wsb + OFF_SELF);
  bf16* qbuf    = (bf16*)(wsb + OFF_Q);
  bf16* svbuf   = (bf16*)(wsb + OFF_SV);
  bf16* hbuf    = (bf16*)(wsb + OFF_H);

  float* out = (float*)d_out;
  float* att_out = out + (size_t)NB * 256;

  dim3 blk(256);
  wprep<<<dim3(160, 10), blk, 0, stream>>>(W_mu, W_var, W_self, W_other, W_q, W_k, W_v, W_a, wsb);
  // z = eps*exp(0.5*logvar)+mu  AND  self_em = relu(x@W_self+b), async-B staged
  gemm_zself<<<dim3(NB / 64, 4), blk, 0, stream>>>(x, WtMu, WtVar, WtSelf,
                                                   b_mu, b_var, b_self, eps, zbuf, selfbuf);
  // q = relu(z@W_q+b_q)  AND  sv = self_em@W_v[256:]+b_v, one launch (async)
  gemm_qsv<<<dim3(NB / 64, 4), blk, 0, stream>>>(zbuf, selfbuf, WtQ, WtV2,
                                                 b_q, b_v, qbuf, svbuf);
  // fused: other_em -> [k | v] unified GEMM -> scores -> softmax -> h
  k_fused<<<NB / 4, dim3(512), 0, stream>>>(x, qbuf, svbuf, WtOther, b_other, WtK, b_k,
                                            WtV1, att_out, hbuf);
  // out = relu([h; self_em] @ W_a + b_a)   (dual-A, async staged)
  gemm_dualA<<<dim3(NB / 64, 2), blk, 0, stream>>>(hbuf, selfbuf, WtA1, WtA2, b_a, out);
}

// Round 12
// 316.340 us; speedup vs baseline: 1.0420x; 1.0401x over previous
//
#include <hip/hip_runtime.h>

typedef __bf16 bf16;
typedef __bf16 bf16x4 __attribute__((ext_vector_type(4)));
typedef __bf16 bf16x8 __attribute__((ext_vector_type(8)));
typedef float  f32x4  __attribute__((ext_vector_type(4)));

// Problem constants
#define NB    16384      // batch
#define NOBS  568
#define NH    256
#define NAG   19         // N_OTHER

// ws byte offsets (all 16B aligned). ALL weights CHUNK-MAJOR [K/32][256][32].
#define OFF_WT_MU    0u          // [18][256][32]
#define OFF_WT_VAR   294912u     // [18][256][32]
#define OFF_WT_SELF  589824u     // [2][256][32]
#define OFF_WT_OTHER 622592u     // [1][256][32]
#define OFF_WT_Q     638976u     // [8][256][32] (chunk-8 overflow -> WT_K)
#define OFF_WT_K     770048u     // [8][256][32] (chunk-8 overflow -> V1)
#define OFF_WT_V1    901120u     // [8][256][32] (chunk-8 overflow -> V2)
#define OFF_WT_V2    1032192u    // [8][256][32] (chunk-8 overflow -> A1)
#define OFF_WT_A1    1163264u    // [8][256][32]
#define OFF_WT_A2    1294336u    // [8][256][32]
#define OFF_Z        1425408u    // [16384][256] bf16
#define OFF_SELF     9814016u
#define OFF_Q        18202624u
#define OFF_SV       26591232u
#define OFF_H        34979840u

static __device__ __forceinline__ unsigned short bfbits(float v) {
  bf16 b = (bf16)v;
  union { bf16 b; unsigned short u; } cvt; cvt.b = b; return cvt.u;
}

// async global->LDS, 16B per lane; dest = wave-uniform base + lane*16
static __device__ __forceinline__ void gload16(const bf16* g, bf16* l) {
  __builtin_amdgcn_global_load_lds(
      (const __attribute__((address_space(1))) void*)g,
      (__attribute__((address_space(3))) void*)(void*)l, 16, 0, 0);
}

// ---------------------------------------------------------------------------
// Weight prep (round-18 version: chunk-major, coalesced reads; unchanged).
// ---------------------------------------------------------------------------
__global__ __launch_bounds__(256) void wprep(
    const float* __restrict__ Wmu, const float* __restrict__ Wvar,
    const float* __restrict__ Wself, const float* __restrict__ Wother,
    const float* __restrict__ Wq, const float* __restrict__ Wk,
    const float* __restrict__ Wv, const float* __restrict__ Wa, char* wsb)
{
  const float* src; bf16* dst; int K, Kp;
  switch (blockIdx.y) {
    case 0: src = Wmu;        dst = (bf16*)(wsb + OFF_WT_MU);    K = 568; Kp = 576; break;
    case 1: src = Wvar;       dst = (bf16*)(wsb + OFF_WT_VAR);   K = 568; Kp = 576; break;
    case 2: src = Wself;      dst = (bf16*)(wsb + OFF_WT_SELF);  K = 36;  Kp = 64;  break;
    case 3: src = Wother;     dst = (bf16*)(wsb + OFF_WT_OTHER); K = 28;  Kp = 32;  break;
    case 4: src = Wq;         dst = (bf16*)(wsb + OFF_WT_Q);     K = 256; Kp = 256; break;
    case 5: src = Wk;         dst = (bf16*)(wsb + OFF_WT_K);     K = 256; Kp = 256; break;
    case 6: src = Wv;         dst = (bf16*)(wsb + OFF_WT_V1);    K = 256; Kp = 256; break;
    case 7: src = Wv + 65536; dst = (bf16*)(wsb + OFF_WT_V2);    K = 256; Kp = 256; break;
    case 8: src = Wa;         dst = (bf16*)(wsb + OFF_WT_A1);    K = 256; Kp = 256; break;
    default: src = Wa + 65536; dst = (bf16*)(wsb + OFF_WT_A2);   K = 256; Kp = 256; break;
  }
  int total = 256 * Kp;
  for (int i = blockIdx.x * 256 + threadIdx.x; i < total; i += gridDim.x * 256) {
    int n = i & 255, kk = (i >> 8) & 31, ch = i >> 13;
    int k = ch * 32 + kk;
    dst[ch * 8192 + n * 32 + kk] = (k < K) ? (bf16)src[k * 256 + n] : (bf16)0.f;
  }
}

// ---------------------------------------------------------------------------
// z + self GEMM (round-18 async-B version, unchanged; proven).
// ---------------------------------------------------------------------------
__global__ __launch_bounds__(256, 3) void gemm_zself(
    const float* __restrict__ x,
    const bf16* __restrict__ WtMuC, const bf16* __restrict__ WtVarC,
    const bf16* __restrict__ WtSelfC,
    const float* __restrict__ b_mu, const float* __restrict__ b_var,
    const float* __restrict__ b_self, const float* __restrict__ eps,
    bf16* __restrict__ zout, bf16* __restrict__ selfout)
{
  __shared__ bf16 lA[2][64 * 40];                  // 10240 B (padded, ds_write)
  __shared__ __align__(16) bf16 lB1[2][128 * 32];  // 16384 B (gload)
  __shared__ __align__(16) bf16 lB2[2][128 * 32];  // 16384 B (gload, z only)

  const int tid = threadIdx.x;
  const int wave = tid >> 6;
  const int lane = tid & 63;
  const int quad = lane >> 4;
  const int m = lane & 15;
  const int rowbase = blockIdx.x * 64;
  const int colbase = (blockIdx.y & 1) * 128;
  const bool isZ = blockIdx.y < 2;
  const int nch = isZ ? 18 : 2;                    // K = 576 or 64
  const bf16* __restrict__ W1 = isZ ? WtMuC : WtSelfC;
  const float* __restrict__ bias = isZ ? b_mu : b_self;

  f32x4 acc[8], accB[8];
  const f32x4 z4 = {0.f, 0.f, 0.f, 0.f};
#pragma unroll
  for (int ct = 0; ct < 8; ++ct) { acc[ct] = z4; accB[ct] = z4; }

  const int ar0 = tid >> 3, afs0 = tid & 7;
  const int ar1 = (tid + 256) >> 3, afs1 = (tid + 256) & 7;

  auto loadA = [&](int kc, int fs, int r, float4& f) {
    int k = kc + fs * 4;
    const float* src = x + (size_t)(rowbase + r) * 568 + k;
    if (k + 4 <= 568) {
      f = *(const float4*)src;
    } else {
      f.x = (k + 0 < 568) ? src[0] : 0.f;
      f.y = (k + 1 < 568) ? src[1] : 0.f;
      f.z = (k + 2 < 568) ? src[2] : 0.f;
      f.w = (k + 3 < 568) ? src[3] : 0.f;
    }
  };
  auto writeA = [&](int buf, int fs, int r, const float4& f) {
    bf16x4 o = {(bf16)f.x, (bf16)f.y, (bf16)f.z, (bf16)f.w};
    *(bf16x4*)(&lA[buf][r * 40 + fs * 4]) = o;
  };
  auto stageB = [&](int buf, int ch) {
    const bf16* s1 = W1 + (size_t)ch * 8192 + colbase * 32 + tid * 8;
    gload16(s1, &lB1[buf][wave * 512]);
    gload16(s1 + 2048, &lB1[buf][2048 + wave * 512]);
    if (isZ) {
      const bf16* s2 = WtVarC + (size_t)ch * 8192 + colbase * 32 + tid * 8;
      gload16(s2, &lB2[buf][wave * 512]);
      gload16(s2 + 2048, &lB2[buf][2048 + wave * 512]);
    }
  };

  {
    float4 f0, f1;
    loadA(0, afs0, ar0, f0);
    loadA(0, afs1, ar1, f1);
    stageB(0, 0);
    writeA(0, afs0, ar0, f0);
    writeA(0, afs1, ar1, f1);
  }
  __syncthreads();

  for (int ch = 0; ch < nch; ++ch) {
    const int cur = ch & 1, nxt = cur ^ 1;
    float4 f0, f1;
    const bool more = (ch + 1 < nch);
    if (more) {
      stageB(nxt, ch + 1);
      loadA((ch + 1) * 32, afs0, ar0, f0);
      loadA((ch + 1) * 32, afs1, ar1, f1);
    }
    bf16x8 afrag = *(const bf16x8*)(&lA[cur][(wave * 16 + m) * 40 + quad * 8]);
#pragma unroll
    for (int ct = 0; ct < 8; ++ct) {
      bf16x8 bfrag = *(const bf16x8*)(&lB1[cur][(ct * 16 + m) * 32 + quad * 8]);
      acc[ct] = __builtin_amdgcn_mfma_f32_16x16x32_bf16(afrag, bfrag, acc[ct], 0, 0, 0);
      if (isZ) {
        bf16x8 b2 = *(const bf16x8*)(&lB2[cur][(ct * 16 + m) * 32 + quad * 8]);
        accB[ct] = __builtin_amdgcn_mfma_f32_16x16x32_bf16(afrag, b2, accB[ct], 0, 0, 0);
      }
    }
    if (more) {
      writeA(nxt, afs0, ar0, f0);
      writeA(nxt, afs1, ar1, f1);
    }
    __syncthreads();
  }

#pragma unroll
  for (int ct = 0; ct < 8; ++ct) {
    const int col = colbase + ct * 16 + m;
    const float bv = bias[col];
#pragma unroll
    for (int r = 0; r < 4; ++r) {
      const size_t row = (size_t)rowbase + wave * 16 + quad * 4 + r;
      float v = acc[ct][r] + bv;
      if (isZ) {
        float lv = accB[ct][r] + b_var[col];
        float zz = eps[row * 256 + col] * __expf(0.5f * lv) + v;
        zout[row * 256 + col] = (bf16)zz;
      } else {
        selfout[row * 256 + col] = (bf16)(v > 0.f ? v : 0.f);
      }
    }
  }
}

// ---------------------------------------------------------------------------
// q + sv GEMM (round-15 async version, 64x128 tiles; proven best config).
// ---------------------------------------------------------------------------
__global__ __launch_bounds__(256, 4) void gemm_qsv(
    const bf16* __restrict__ zb, const bf16* __restrict__ selfb,
    const bf16* __restrict__ WtQc, const bf16* __restrict__ WtV2c,
    const float* __restrict__ b_q, const float* __restrict__ b_v,
    bf16* __restrict__ qout, bf16* __restrict__ svout)
{
  __shared__ __align__(16) bf16 lA[2][64 * 32];
  __shared__ __align__(16) bf16 lB[2][128 * 32];

  const int tid = threadIdx.x;
  const int wave = tid >> 6;
  const int lane = tid & 63;
  const int quad = lane >> 4;
  const int m = lane & 15;
  const int rowbase = blockIdx.x * 64;
  const int colbase = (blockIdx.y & 1) * 128;
  const bool isQ = blockIdx.y < 2;
  const bf16* __restrict__ Ap = isQ ? zb : selfb;
  const bf16* __restrict__ Wc = isQ ? WtQc : WtV2c;
  const float* __restrict__ bias = isQ ? b_q : b_v;
  bf16* __restrict__ outp = isQ ? qout : svout;

  f32x4 acc[8];
  const f32x4 z4 = {0.f, 0.f, 0.f, 0.f};
#pragma unroll
  for (int ct = 0; ct < 8; ++ct) acc[ct] = z4;

  const size_t arow = (size_t)(rowbase + (tid >> 2)) * 256 + (tid & 3) * 8;
  const size_t bbase = (size_t)colbase * 32 + (size_t)tid * 8;

  gload16(Ap + arow, &lA[0][wave * 512]);
  gload16(Wc + bbase, &lB[0][wave * 512]);
  gload16(Wc + bbase + 2048, &lB[0][2048 + wave * 512]);
  __syncthreads();

#pragma unroll
  for (int ch = 0; ch < 8; ++ch) {
    const int cur = ch & 1;
    if (ch < 7) {
      const int nxt = cur ^ 1;
      const size_t cof = (size_t)(ch + 1) * 8192;
      gload16(Ap + arow + (ch + 1) * 32, &lA[nxt][wave * 512]);
      gload16(Wc + cof + bbase, &lB[nxt][wave * 512]);
      gload16(Wc + cof + bbase + 2048, &lB[nxt][2048 + wave * 512]);
    }
    bf16x8 afrag = *(const bf16x8*)(&lA[cur][(wave * 16 + m) * 32 + quad * 8]);
#pragma unroll
    for (int ct = 0; ct < 8; ++ct) {
      bf16x8 bfrag = *(const bf16x8*)(&lB[cur][(ct * 16 + m) * 32 + quad * 8]);
      acc[ct] = __builtin_amdgcn_mfma_f32_16x16x32_bf16(afrag, bfrag, acc[ct], 0, 0, 0);
    }
    __syncthreads();
  }

#pragma unroll
  for (int ct = 0; ct < 8; ++ct) {
    const int col = colbase + ct * 16 + m;
    const float bv = bias[col];
#pragma unroll
    for (int r = 0; r < 4; ++r) {
      const size_t row = (size_t)rowbase + wave * 16 + quad * 4 + r;
      float v = acc[ct][r] + bv;
      if (isQ) v = (v > 0.f ? v : 0.f);
      outp[row * 256 + col] = (bf16)v;
    }
  }
}

// ---------------------------------------------------------------------------
// dual-A GEMM (round-15 async version, 64x128 tiles; proven best config).
// ---------------------------------------------------------------------------
__global__ __launch_bounds__(256, 4) void gemm_dualA(
    const bf16* __restrict__ A1, const bf16* __restrict__ A2,
    const bf16* __restrict__ Wt1c, const bf16* __restrict__ Wt2c,
    const float* __restrict__ bias, float* __restrict__ outp)
{
  __shared__ __align__(16) bf16 lA[2][64 * 32];
  __shared__ __align__(16) bf16 lB[2][128 * 32];

  const int tid = threadIdx.x;
  const int wave = tid >> 6;
  const int lane = tid & 63;
  const int quad = lane >> 4;
  const int m = lane & 15;
  const int rowbase = blockIdx.x * 64;
  const int colbase = blockIdx.y * 128;

  f32x4 acc[8];
  const f32x4 z4 = {0.f, 0.f, 0.f, 0.f};
#pragma unroll
  for (int ct = 0; ct < 8; ++ct) acc[ct] = z4;

  const size_t arow = (size_t)(rowbase + (tid >> 2)) * 256 + (tid & 3) * 8;
  const size_t bbase = (size_t)colbase * 32 + (size_t)tid * 8;

  auto stageT = [&](int buf, int t) {
    const int ch = t & 7;
    const bf16* Astep = (t < 8) ? A1 : A2;
    const bf16* Wstep = (t < 8) ? Wt1c : Wt2c;
    const size_t cof = (size_t)ch * 8192;
    gload16(Astep + arow + ch * 32, &lA[buf][wave * 512]);
    gload16(Wstep + cof + bbase, &lB[buf][wave * 512]);
    gload16(Wstep + cof + bbase + 2048, &lB[buf][2048 + wave * 512]);
  };

  stageT(0, 0);
  __syncthreads();

#pragma unroll
  for (int t = 0; t < 16; ++t) {
    const int cur = t & 1;
    if (t < 15) stageT(cur ^ 1, t + 1);
    bf16x8 afrag = *(const bf16x8*)(&lA[cur][(wave * 16 + m) * 32 + quad * 8]);
#pragma unroll
    for (int ct = 0; ct < 8; ++ct) {
      bf16x8 bfrag = *(const bf16x8*)(&lB[cur][(ct * 16 + m) * 32 + quad * 8]);
      acc[ct] = __builtin_amdgcn_mfma_f32_16x16x32_bf16(afrag, bfrag, acc[ct], 0, 0, 0);
    }
    __syncthreads();
  }

#pragma unroll
  for (int ct = 0; ct < 8; ++ct) {
    const int col = colbase + ct * 16 + m;
    const float bv = bias[col];
#pragma unroll
    for (int r = 0; r < 4; ++r) {
      const size_t row = (size_t)rowbase + wave * 16 + quad * 4 + r;
      float v = acc[ct][r] + bv;
      outp[row * 256 + col] = (v > 0.f ? v : 0.f);
    }
  }
}

// ---------------------------------------------------------------------------
// Fused attention -- ROUND-22 CHANGE (only one): phase-1 epilogue writes
// other_em to ldsO via direct per-lane ds_write_b16 (3 ops/element) instead
// of the bfbits+shfl_xor+pack+predicated-dword dance (7 ops/element); bit-
// identical LDS contents. Adjacent m-lanes share a dword (2 lanes/bank =
// free, m136). setprio DROPPED (measured null r11: lockstep main loop has
// no role diversity -- m190 regime, not m191). Rest byte-identical to the
// proven round-8 version (328.0 us total).
// ---------------------------------------------------------------------------
__global__ __launch_bounds__(512, 4) void k_fused(
    const float* __restrict__ x, const bf16* __restrict__ qb,
    const bf16* __restrict__ svb,
    const bf16* __restrict__ WtOther, const float* __restrict__ b_other,
    const bf16* __restrict__ WtKc, const float* __restrict__ b_k,
    const bf16* __restrict__ WtVc,
    float* __restrict__ att_out, bf16* __restrict__ hb)
{
  __shared__ bf16 ldsO[80 * 264];     // 42240 B  other_em (16B-group stride 33)
  __shared__ bf16 ldsA1[80 * 40];     //  6400 B  agents tile; REUSED: spart/attl
  __shared__ bf16 qh16[1024];         //  2048 B  q (bf16); REUSED: h partials
  __shared__ bf16 svl16[1024];        //  2048 B  sv (bf16)
  float* spart = (float*)ldsA1;        // [0..320)  floats: 4 K-waves x 80 rows
  float* attl  = (float*)ldsA1 + 320;  // [320..400) floats: att weights, row order

  const int tid = threadIdx.x, wave = tid >> 6, lane = tid & 63;
  const int quad = lane >> 4, m = lane & 15;
  const int b0 = blockIdx.x * 4;
  const int kvw = wave & 3;            // column-group within K or V half
  const bool isV = wave >= 4;

  // ---- phase 0: stage q, sv (bf16 copies), agents_info (interleaved rows)
  ((unsigned*)qh16)[tid]  = ((const unsigned*)(qb  + (size_t)b0 * 256))[tid];
  ((unsigned*)svl16)[tid] = ((const unsigned*)(svb + (size_t)b0 * 256))[tid];
  for (int i = tid; i < 80 * 16; i += 512) {
    int r = i >> 4, kk = (i & 15) * 2;   // lds row r = agent*4 + batch
    int n = r >> 2, bb = r & 3;
    float v0 = 0.f, v1 = 0.f;
    if (n < 19) {
      const float* base = x + (size_t)(b0 + bb) * NOBS + 36 + n * 28;
      if (kk < 28) v0 = base[kk];
      if (kk + 1 < 28) v1 = base[kk + 1];
    }
    unsigned u0 = bfbits(v0), u1 = bfbits(v1);
    *(unsigned*)(ldsA1 + r * 40 + kk) = u0 | (u1 << 16);
  }

  const f32x4 z4 = {0.f, 0.f, 0.f, 0.f};

  // ---- issue first main-loop B buffer early (independent of all LDS)
  const bf16* __restrict__ Bc = isV ? WtVc : WtKc;
  const int cb = (kvw * 64 + m) * 32 + quad * 8;   // ((4*kvw+c)*16+m)*32+q*8 == cb+c*512
  bf16x8 bE[4];
#pragma unroll
  for (int c = 0; c < 4; ++c) bE[c] = *(const bf16x8*)(Bc + cb + c * 512);

  __syncthreads();

  // ---- phase 1: other_em = relu(A1 @ WtOther^T + b_other), K=32.
  {
    float bo[2];
    bf16x8 bfr[2];
#pragma unroll
    for (int c = 0; c < 2; ++c) {
      int col = (2 * wave + c) * 16 + m;
      bo[c] = b_other[col];
      bfr[c] = *(const bf16x8*)(WtOther + col * 32 + quad * 8);
    }
    f32x4 acc1[5][2];
#pragma unroll
    for (int rt = 0; rt < 5; ++rt) {
      bf16x8 a = *(const bf16x8*)(ldsA1 + (rt * 16 + m) * 40 + quad * 8);
#pragma unroll
      for (int c = 0; c < 2; ++c)
        acc1[rt][c] = __builtin_amdgcn_mfma_f32_16x16x32_bf16(a, bfr[c], z4, 0, 0, 0);
    }
    // direct b16 stores: every lane writes its own column (bit-identical
    // values; adjacent m-lanes share a dword -> 2 lanes/bank, free)
#pragma unroll
    for (int rt = 0; rt < 5; ++rt)
#pragma unroll
      for (int c = 0; c < 2; ++c) {
        int col = (2 * wave + c) * 16 + m;
#pragma unroll
        for (int r = 0; r < 4; ++r) {
          float v = acc1[rt][c][r] + bo[c];
          v = v > 0.f ? v : 0.f;
          int rowl = rt * 16 + quad * 4 + r;
          ldsO[rowl * 264 + col] = (bf16)v;
        }
      }
  }
  __syncthreads();   // ldsA1 (agents tile) dead from here; spart/attl overlay

  // ---- unified main GEMM: 80 rows x 512 cols ([WtK | WtV]), 8 chunks,
  // ping-pong software pipeline (prefetch distance 1, no conditionals).
  f32x4 acc[5][4];
#pragma unroll
  for (int rt = 0; rt < 5; ++rt)
#pragma unroll
    for (int c = 0; c < 4; ++c) acc[rt][c] = z4;

  {
#pragma unroll 1
    for (int ch = 0; ch < 8; ch += 2) {
      bf16x8 bO[4];
#pragma unroll
      for (int c = 0; c < 4; ++c)
        bO[c] = *(const bf16x8*)(Bc + (size_t)(ch + 1) * 8192 + cb + c * 512);
      const int kc0 = ch * 32;
#pragma unroll
      for (int rt = 0; rt < 5; ++rt) {
        bf16x8 a = *(const bf16x8*)(ldsO + (rt * 16 + m) * 264 + kc0 + quad * 8);
#pragma unroll
        for (int c = 0; c < 4; ++c)
          acc[rt][c] = __builtin_amdgcn_mfma_f32_16x16x32_bf16(a, bE[c], acc[rt][c], 0, 0, 0);
      }
      // prefetch ch+2; at ch==6 this reads chunk 8 = adjacent weight region
#pragma unroll
      for (int c = 0; c < 4; ++c)
        bE[c] = *(const bf16x8*)(Bc + (size_t)(ch + 2) * 8192 + cb + c * 512);
      const int kc1 = kc0 + 32;
#pragma unroll
      for (int rt = 0; rt < 5; ++rt) {
        bf16x8 a = *(const bf16x8*)(ldsO + (rt * 16 + m) * 264 + kc1 + quad * 8);
#pragma unroll
        for (int c = 0; c < 4; ++c)
          acc[rt][c] = __builtin_amdgcn_mfma_f32_16x16x32_bf16(a, bO[c], acc[rt][c], 0, 0, 0);
      }
    }
  }

  // ---- K-waves: scores = (relu(k)+b_k) . q, reduce over lanes -> spart
  if (!isV) {
    float qreg[4][4], bkreg[4];
#pragma unroll
    for (int c = 0; c < 4; ++c) {
      int col = (4 * wave + c) * 16 + m;
      bkreg[c] = b_k[col];
#pragma unroll
      for (int r = 0; r < 4; ++r) qreg[c][r] = (float)qh16[r * 256 + col];
    }
#pragma unroll
    for (int rt = 0; rt < 5; ++rt) {
      float part[4] = {0.f, 0.f, 0.f, 0.f};
#pragma unroll
      for (int c = 0; c < 4; ++c) {
#pragma unroll
        for (int r = 0; r < 4; ++r) {
          float kv = acc[rt][c][r] + bkreg[c];
          kv = kv > 0.f ? kv : 0.f;
          part[r] += kv * qreg[c][r];
        }
      }
#pragma unroll
      for (int r = 0; r < 4; ++r) {
        float p = part[r];
        p += __shfl_xor(p, 1, 64);
        p += __shfl_xor(p, 2, 64);
        p += __shfl_xor(p, 4, 64);
        p += __shfl_xor(p, 8, 64);
        if (m == 0) spart[wave * 80 + rt * 16 + quad * 4 + r] = p;
      }
    }
  }
  __syncthreads();

  // ---- softmax: wave w = batch w, lanes 0-18 = agents (width-32 tree)
  if (!isV && lane < 32) {
    const int bb = wave, j = lane;      // batch, agent
    float s = -1e30f;
    if (j < 19) {
      int row = j * 4 + bb;             // interleaved: row = agent*4 + batch
      s = (spart[row] + spart[80 + row] + spart[160 + row] + spart[240 + row]) * 0.0625f;
    }
    float mx = s;
#pragma unroll
    for (int off = 16; off >= 1; off >>= 1) mx = fmaxf(mx, __shfl_xor(mx, off, 32));
    float e = (j < 19) ? __expf(s - mx) : 0.f;
    float sum = e;
#pragma unroll
    for (int off = 16; off >= 1; off >>= 1) sum += __shfl_xor(sum, off, 32);
    float inv = 1.f / sum;
    float a = e * inv;
    if (j < 20) attl[j * 4 + bb] = a;   // j==19 writes the zero pad row
    if (j < 19) att_out[(size_t)(b0 + bb) * 19 + j] = a;
  }
  __syncthreads();

  // ---- V-waves: epilogue  h = sum_rows att * relu(v + sv)
  if (isV) {
    float svreg[4][4];
#pragma unroll
    for (int c = 0; c < 4; ++c) {
      int col = (4 * kvw + c) * 16 + m;
#pragma unroll
      for (int r = 0; r < 4; ++r) svreg[c][r] = (float)svl16[r * 256 + col];
    }
    float hacc[4][4];   // [c][batch==r]
#pragma unroll
    for (int c = 0; c < 4; ++c)
#pragma unroll
      for (int r = 0; r < 4; ++r) hacc[c][r] = 0.f;
#pragma unroll
    for (int rt = 0; rt < 5; ++rt) {
      float av[4];
#pragma unroll
      for (int r = 0; r < 4; ++r) av[r] = attl[rt * 16 + quad * 4 + r];
#pragma unroll
      for (int c = 0; c < 4; ++c) {
#pragma unroll
        for (int r = 0; r < 4; ++r) {
          float v = acc[rt][c][r] + svreg[c][r];
          v = v > 0.f ? v : 0.f;
          hacc[c][r] += v * av[r];
        }
      }
    }
#pragma unroll
    for (int c = 0; c < 4; ++c)
#pragma unroll
      for (int r = 0; r < 4; ++r) {
        float h = hacc[c][r];
        h += __shfl_xor(h, 16, 64);
        h += __shfl_xor(h, 32, 64);
        if (quad == 0) qh16[r * 256 + (4 * kvw + c) * 16 + m] = (bf16)h;
      }
  }
  __syncthreads();
  ((unsigned*)(hb + (size_t)b0 * 256))[tid] = ((const unsigned*)qh16)[tid];
}

// ---------------------------------------------------------------------------
extern "C" void kernel_launch(void* const* d_in, const int* in_sizes, int n_in,
                              void* d_out, int out_size, void* d_ws, size_t ws_size,
                              hipStream_t stream) {
  (void)in_sizes; (void)n_in; (void)out_size; (void)ws_size;
  const float* x      = (const float*)d_in[0];
  const float* eps    = (const float*)d_in[1];
  const float* W_mu   = (const float*)d_in[2];
  const float* b_mu   = (const float*)d_in[3];
  const float* W_var  = (const float*)d_in[4];
  const float* b_var  = (const float*)d_in[5];
  const float* W_self = (const float*)d_in[6];
  const float* b_self = (const float*)d_in[7];
  const float* W_other= (const float*)d_in[8];
  const float* b_other= (const float*)d_in[9];
  const float* W_q    = (const float*)d_in[10];
  const float* b_q    = (const float*)d_in[11];
  const float* W_k    = (const float*)d_in[12];
  const float* b_k    = (const float*)d_in[13];
  const float* W_v    = (const float*)d_in[14];
  const float* b_v    = (const float*)d_in[15];
  const float* W_a    = (const float*)d_in[16];
  const float* b_a    = (const float*)d_in[17];

  char* wsb = (char*)d_ws;
  bf16* WtMu    = (bf16*)(wsb + OFF_WT_MU);
  bf16* WtVar   = (bf16*)(wsb + OFF_WT_VAR);
  bf16* WtSelf  = (bf16*)(wsb + OFF_WT_SELF);
  bf16* WtOther = (bf16*)(wsb + OFF_WT_OTHER);
  bf16* WtQ     = (bf16*)(wsb + OFF_WT_Q);
  bf16* WtK     = (bf16*)(wsb + OFF_WT_K);
  bf16* WtV1    = (bf16*)(wsb + OFF_WT_V1);
  bf16* WtV2    = (bf16*)(wsb + OFF_WT_V2);
  bf16* WtA1    = (bf16*)(wsb + OFF_WT_A1);
  bf16* WtA2    = (bf16*)(wsb + OFF_WT_A2);
  bf16* zbuf    = (bf16*)(wsb + OFF_Z);
  bf16* selfbuf = (bf16*)(wsb + OFF_SELF);
  bf16* qbuf    = (bf16*)(wsb + OFF_Q);
  bf16* svbuf   = (bf16*)(wsb + OFF_SV);
  bf16* hbuf    = (bf16*)(wsb + OFF_H);

  float* out = (float*)d_out;
  float* att_out = out + (size_t)NB * 256;

  dim3 blk(256);
  wprep<<<dim3(160, 10), blk, 0, stream>>>(W_mu, W_var, W_self, W_other, W_q, W_k, W_v, W_a, wsb);
  // z = eps*exp(0.5*logvar)+mu  AND  self_em = relu(x@W_self+b), async-B staged
  gemm_zself<<<dim3(NB / 64, 4), blk, 0, stream>>>(x, WtMu, WtVar, WtSelf,
                                                   b_mu, b_var, b_self, eps, zbuf, selfbuf);
  // q = relu(z@W_q+b_q)  AND  sv = self_em@W_v[256:]+b_v, one launch (async)
  gemm_qsv<<<dim3(NB / 64, 4), blk, 0, stream>>>(zbuf, selfbuf, WtQ, WtV2,
                                                 b_q, b_v, qbuf, svbuf);
  // fused: other_em -> [k | v] unified GEMM -> scores -> softmax -> h
  k_fused<<<NB / 4, dim3(512), 0, stream>>>(x, qbuf, svbuf, WtOther, b_other, WtK, b_k,
                                            WtV1, att_out, hbuf);
  // out = relu([h; self_em] @ W_a + b_a)   (dual-A, async staged)
  gemm_dualA<<<dim3(NB / 64, 2), blk, 0, stream>>>(hbuf, selfbuf, WtA1, WtA2, b_a, out);
}

// Round 13
// 310.798 us; speedup vs baseline: 1.0606x; 1.0178x over previous
//
#include <hip/hip_runtime.h>

typedef __bf16 bf16;
typedef __bf16 bf16x4 __attribute__((ext_vector_type(4)));
typedef __bf16 bf16x8 __attribute__((ext_vector_type(8)));
typedef float  f32x4  __attribute__((ext_vector_type(4)));

// Problem constants
#define NB    16384      // batch
#define NOBS  568
#define NH    256
#define NAG   19         // N_OTHER

// ws byte offsets (all 16B aligned). ALL weights CHUNK-MAJOR [K/32][256][32].
#define OFF_WT_MU    0u          // [18][256][32]
#define OFF_WT_VAR   294912u     // [18][256][32]
#define OFF_WT_SELF  589824u     // [2][256][32]
#define OFF_WT_OTHER 622592u     // [1][256][32]
#define OFF_WT_Q     638976u     // [8][256][32] (chunk-8 overflow -> WT_K)
#define OFF_WT_K     770048u     // [8][256][32] (chunk-8 overflow -> V1)
#define OFF_WT_V1    901120u     // [8][256][32] (chunk-8 overflow -> V2)
#define OFF_WT_V2    1032192u    // [8][256][32] (chunk-8 overflow -> A1)
#define OFF_WT_A1    1163264u    // [8][256][32]
#define OFF_WT_A2    1294336u    // [8][256][32]
#define OFF_Z        1425408u    // [16384][256] bf16
#define OFF_SELF     9814016u
#define OFF_Q        18202624u
#define OFF_SV       26591232u
#define OFF_H        34979840u

static __device__ __forceinline__ unsigned short bfbits(float v) {
  bf16 b = (bf16)v;
  union { bf16 b; unsigned short u; } cvt; cvt.b = b; return cvt.u;
}

// async global->LDS, 16B per lane; dest = wave-uniform base + lane*16
static __device__ __forceinline__ void gload16(const bf16* g, bf16* l) {
  __builtin_amdgcn_global_load_lds(
      (const __attribute__((address_space(1))) void*)g,
      (__attribute__((address_space(3))) void*)(void*)l, 16, 0, 0);
}

// ---------------------------------------------------------------------------
// Weight prep (round-18 version: chunk-major, coalesced reads; unchanged).
// ---------------------------------------------------------------------------
__global__ __launch_bounds__(256) void wprep(
    const float* __restrict__ Wmu, const float* __restrict__ Wvar,
    const float* __restrict__ Wself, const float* __restrict__ Wother,
    const float* __restrict__ Wq, const float* __restrict__ Wk,
    const float* __restrict__ Wv, const float* __restrict__ Wa, char* wsb)
{
  const float* src; bf16* dst; int K, Kp;
  switch (blockIdx.y) {
    case 0: src = Wmu;        dst = (bf16*)(wsb + OFF_WT_MU);    K = 568; Kp = 576; break;
    case 1: src = Wvar;       dst = (bf16*)(wsb + OFF_WT_VAR);   K = 568; Kp = 576; break;
    case 2: src = Wself;      dst = (bf16*)(wsb + OFF_WT_SELF);  K = 36;  Kp = 64;  break;
    case 3: src = Wother;     dst = (bf16*)(wsb + OFF_WT_OTHER); K = 28;  Kp = 32;  break;
    case 4: src = Wq;         dst = (bf16*)(wsb + OFF_WT_Q);     K = 256; Kp = 256; break;
    case 5: src = Wk;         dst = (bf16*)(wsb + OFF_WT_K);     K = 256; Kp = 256; break;
    case 6: src = Wv;         dst = (bf16*)(wsb + OFF_WT_V1);    K = 256; Kp = 256; break;
    case 7: src = Wv + 65536; dst = (bf16*)(wsb + OFF_WT_V2);    K = 256; Kp = 256; break;
    case 8: src = Wa;         dst = (bf16*)(wsb + OFF_WT_A1);    K = 256; Kp = 256; break;
    default: src = Wa + 65536; dst = (bf16*)(wsb + OFF_WT_A2);   K = 256; Kp = 256; break;
  }
  int total = 256 * Kp;
  for (int i = blockIdx.x * 256 + threadIdx.x; i < total; i += gridDim.x * 256) {
    int n = i & 255, kk = (i >> 8) & 31, ch = i >> 13;
    int k = ch * 32 + kk;
    dst[ch * 8192 + n * 32 + kk] = (k < K) ? (bf16)src[k * 256 + n] : (bf16)0.f;
  }
}

// ---------------------------------------------------------------------------
// z + self GEMM (round-18 async-B version, unchanged; proven).
// ---------------------------------------------------------------------------
__global__ __launch_bounds__(256, 3) void gemm_zself(
    const float* __restrict__ x,
    const bf16* __restrict__ WtMuC, const bf16* __restrict__ WtVarC,
    const bf16* __restrict__ WtSelfC,
    const float* __restrict__ b_mu, const float* __restrict__ b_var,
    const float* __restrict__ b_self, const float* __restrict__ eps,
    bf16* __restrict__ zout, bf16* __restrict__ selfout)
{
  __shared__ bf16 lA[2][64 * 40];                  // 10240 B (padded, ds_write)
  __shared__ __align__(16) bf16 lB1[2][128 * 32];  // 16384 B (gload)
  __shared__ __align__(16) bf16 lB2[2][128 * 32];  // 16384 B (gload, z only)

  const int tid = threadIdx.x;
  const int wave = tid >> 6;
  const int lane = tid & 63;
  const int quad = lane >> 4;
  const int m = lane & 15;
  const int rowbase = blockIdx.x * 64;
  const int colbase = (blockIdx.y & 1) * 128;
  const bool isZ = blockIdx.y < 2;
  const int nch = isZ ? 18 : 2;                    // K = 576 or 64
  const bf16* __restrict__ W1 = isZ ? WtMuC : WtSelfC;
  const float* __restrict__ bias = isZ ? b_mu : b_self;

  f32x4 acc[8], accB[8];
  const f32x4 z4 = {0.f, 0.f, 0.f, 0.f};
#pragma unroll
  for (int ct = 0; ct < 8; ++ct) { acc[ct] = z4; accB[ct] = z4; }

  const int ar0 = tid >> 3, afs0 = tid & 7;
  const int ar1 = (tid + 256) >> 3, afs1 = (tid + 256) & 7;

  auto loadA = [&](int kc, int fs, int r, float4& f) {
    int k = kc + fs * 4;
    const float* src = x + (size_t)(rowbase + r) * 568 + k;
    if (k + 4 <= 568) {
      f = *(const float4*)src;
    } else {
      f.x = (k + 0 < 568) ? src[0] : 0.f;
      f.y = (k + 1 < 568) ? src[1] : 0.f;
      f.z = (k + 2 < 568) ? src[2] : 0.f;
      f.w = (k + 3 < 568) ? src[3] : 0.f;
    }
  };
  auto writeA = [&](int buf, int fs, int r, const float4& f) {
    bf16x4 o = {(bf16)f.x, (bf16)f.y, (bf16)f.z, (bf16)f.w};
    *(bf16x4*)(&lA[buf][r * 40 + fs * 4]) = o;
  };
  auto stageB = [&](int buf, int ch) {
    const bf16* s1 = W1 + (size_t)ch * 8192 + colbase * 32 + tid * 8;
    gload16(s1, &lB1[buf][wave * 512]);
    gload16(s1 + 2048, &lB1[buf][2048 + wave * 512]);
    if (isZ) {
      const bf16* s2 = WtVarC + (size_t)ch * 8192 + colbase * 32 + tid * 8;
      gload16(s2, &lB2[buf][wave * 512]);
      gload16(s2 + 2048, &lB2[buf][2048 + wave * 512]);
    }
  };

  {
    float4 f0, f1;
    loadA(0, afs0, ar0, f0);
    loadA(0, afs1, ar1, f1);
    stageB(0, 0);
    writeA(0, afs0, ar0, f0);
    writeA(0, afs1, ar1, f1);
  }
  __syncthreads();

  for (int ch = 0; ch < nch; ++ch) {
    const int cur = ch & 1, nxt = cur ^ 1;
    float4 f0, f1;
    const bool more = (ch + 1 < nch);
    if (more) {
      stageB(nxt, ch + 1);
      loadA((ch + 1) * 32, afs0, ar0, f0);
      loadA((ch + 1) * 32, afs1, ar1, f1);
    }
    bf16x8 afrag = *(const bf16x8*)(&lA[cur][(wave * 16 + m) * 40 + quad * 8]);
#pragma unroll
    for (int ct = 0; ct < 8; ++ct) {
      bf16x8 bfrag = *(const bf16x8*)(&lB1[cur][(ct * 16 + m) * 32 + quad * 8]);
      acc[ct] = __builtin_amdgcn_mfma_f32_16x16x32_bf16(afrag, bfrag, acc[ct], 0, 0, 0);
      if (isZ) {
        bf16x8 b2 = *(const bf16x8*)(&lB2[cur][(ct * 16 + m) * 32 + quad * 8]);
        accB[ct] = __builtin_amdgcn_mfma_f32_16x16x32_bf16(afrag, b2, accB[ct], 0, 0, 0);
      }
    }
    if (more) {
      writeA(nxt, afs0, ar0, f0);
      writeA(nxt, afs1, ar1, f1);
    }
    __syncthreads();
  }

#pragma unroll
  for (int ct = 0; ct < 8; ++ct) {
    const int col = colbase + ct * 16 + m;
    const float bv = bias[col];
#pragma unroll
    for (int r = 0; r < 4; ++r) {
      const size_t row = (size_t)rowbase + wave * 16 + quad * 4 + r;
      float v = acc[ct][r] + bv;
      if (isZ) {
        float lv = accB[ct][r] + b_var[col];
        float zz = eps[row * 256 + col] * __expf(0.5f * lv) + v;
        zout[row * 256 + col] = (bf16)zz;
      } else {
        selfout[row * 256 + col] = (bf16)(v > 0.f ? v : 0.f);
      }
    }
  }
}

// ---------------------------------------------------------------------------
// q + sv GEMM -- ROUND-23: __launch_bounds__(256,6) (was 4). LDS 24 KB
// permits 6 blocks/CU -> 24 waves/CU; reg estimate ~70 < 85 budget.
// Body unchanged (proven).
// ---------------------------------------------------------------------------
__global__ __launch_bounds__(256, 6) void gemm_qsv(
    const bf16* __restrict__ zb, const bf16* __restrict__ selfb,
    const bf16* __restrict__ WtQc, const bf16* __restrict__ WtV2c,
    const float* __restrict__ b_q, const float* __restrict__ b_v,
    bf16* __restrict__ qout, bf16* __restrict__ svout)
{
  __shared__ __align__(16) bf16 lA[2][64 * 32];
  __shared__ __align__(16) bf16 lB[2][128 * 32];

  const int tid = threadIdx.x;
  const int wave = tid >> 6;
  const int lane = tid & 63;
  const int quad = lane >> 4;
  const int m = lane & 15;
  const int rowbase = blockIdx.x * 64;
  const int colbase = (blockIdx.y & 1) * 128;
  const bool isQ = blockIdx.y < 2;
  const bf16* __restrict__ Ap = isQ ? zb : selfb;
  const bf16* __restrict__ Wc = isQ ? WtQc : WtV2c;
  const float* __restrict__ bias = isQ ? b_q : b_v;
  bf16* __restrict__ outp = isQ ? qout : svout;

  f32x4 acc[8];
  const f32x4 z4 = {0.f, 0.f, 0.f, 0.f};
#pragma unroll
  for (int ct = 0; ct < 8; ++ct) acc[ct] = z4;

  const size_t arow = (size_t)(rowbase + (tid >> 2)) * 256 + (tid & 3) * 8;
  const size_t bbase = (size_t)colbase * 32 + (size_t)tid * 8;

  gload16(Ap + arow, &lA[0][wave * 512]);
  gload16(Wc + bbase, &lB[0][wave * 512]);
  gload16(Wc + bbase + 2048, &lB[0][2048 + wave * 512]);
  __syncthreads();

#pragma unroll
  for (int ch = 0; ch < 8; ++ch) {
    const int cur = ch & 1;
    if (ch < 7) {
      const int nxt = cur ^ 1;
      const size_t cof = (size_t)(ch + 1) * 8192;
      gload16(Ap + arow + (ch + 1) * 32, &lA[nxt][wave * 512]);
      gload16(Wc + cof + bbase, &lB[nxt][wave * 512]);
      gload16(Wc + cof + bbase + 2048, &lB[nxt][2048 + wave * 512]);
    }
    bf16x8 afrag = *(const bf16x8*)(&lA[cur][(wave * 16 + m) * 32 + quad * 8]);
#pragma unroll
    for (int ct = 0; ct < 8; ++ct) {
      bf16x8 bfrag = *(const bf16x8*)(&lB[cur][(ct * 16 + m) * 32 + quad * 8]);
      acc[ct] = __builtin_amdgcn_mfma_f32_16x16x32_bf16(afrag, bfrag, acc[ct], 0, 0, 0);
    }
    __syncthreads();
  }

#pragma unroll
  for (int ct = 0; ct < 8; ++ct) {
    const int col = colbase + ct * 16 + m;
    const float bv = bias[col];
#pragma unroll
    for (int r = 0; r < 4; ++r) {
      const size_t row = (size_t)rowbase + wave * 16 + quad * 4 + r;
      float v = acc[ct][r] + bv;
      if (isQ) v = (v > 0.f ? v : 0.f);
      outp[row * 256 + col] = (bf16)v;
    }
  }
}

// ---------------------------------------------------------------------------
// dual-A GEMM -- ROUND-23: 64x64 tiles, grid (256,4) (was 64x128, (256,2)).
// 4 blocks/CU -> 16 waves/CU (was 8) in this latency-bound 16-step chain;
// per step now {2 gloads + 4 MFMA + barrier}. Same K-order -> bit-identical.
// LDS 16 KB.
// ---------------------------------------------------------------------------
__global__ __launch_bounds__(256, 4) void gemm_dualA(
    const bf16* __restrict__ A1, const bf16* __restrict__ A2,
    const bf16* __restrict__ Wt1c, const bf16* __restrict__ Wt2c,
    const float* __restrict__ bias, float* __restrict__ outp)
{
  __shared__ __align__(16) bf16 lA[2][64 * 32];
  __shared__ __align__(16) bf16 lB[2][64 * 32];

  const int tid = threadIdx.x;
  const int wave = tid >> 6;
  const int lane = tid & 63;
  const int quad = lane >> 4;
  const int m = lane & 15;
  const int rowbase = blockIdx.x * 64;
  const int colbase = blockIdx.y * 64;

  f32x4 acc[4];
  const f32x4 z4 = {0.f, 0.f, 0.f, 0.f};
#pragma unroll
  for (int ct = 0; ct < 4; ++ct) acc[ct] = z4;

  const size_t arow = (size_t)(rowbase + (tid >> 2)) * 256 + (tid & 3) * 8;
  const size_t bbase = (size_t)colbase * 32 + (size_t)tid * 8;

  auto stageT = [&](int buf, int t) {
    const int ch = t & 7;
    const bf16* Astep = (t < 8) ? A1 : A2;
    const bf16* Wstep = (t < 8) ? Wt1c : Wt2c;
    const size_t cof = (size_t)ch * 8192;
    gload16(Astep + arow + ch * 32, &lA[buf][wave * 512]);
    gload16(Wstep + cof + bbase, &lB[buf][wave * 512]);
  };

  stageT(0, 0);
  __syncthreads();

#pragma unroll
  for (int t = 0; t < 16; ++t) {
    const int cur = t & 1;
    if (t < 15) stageT(cur ^ 1, t + 1);
    bf16x8 afrag = *(const bf16x8*)(&lA[cur][(wave * 16 + m) * 32 + quad * 8]);
#pragma unroll
    for (int ct = 0; ct < 4; ++ct) {
      bf16x8 bfrag = *(const bf16x8*)(&lB[cur][(ct * 16 + m) * 32 + quad * 8]);
      acc[ct] = __builtin_amdgcn_mfma_f32_16x16x32_bf16(afrag, bfrag, acc[ct], 0, 0, 0);
    }
    __syncthreads();
  }

#pragma unroll
  for (int ct = 0; ct < 4; ++ct) {
    const int col = colbase + ct * 16 + m;
    const float bv = bias[col];
#pragma unroll
    for (int r = 0; r < 4; ++r) {
      const size_t row = (size_t)rowbase + wave * 16 + quad * 4 + r;
      float v = acc[ct][r] + bv;
      outp[row * 256 + col] = (v > 0.f ? v : 0.f);
    }
  }
}

// ---------------------------------------------------------------------------
// Fused attention (round-22 version: direct-b16 phase-1 epilogue; proven
// 144.8 us; unchanged).
// ---------------------------------------------------------------------------
__global__ __launch_bounds__(512, 4) void k_fused(
    const float* __restrict__ x, const bf16* __restrict__ qb,
    const bf16* __restrict__ svb,
    const bf16* __restrict__ WtOther, const float* __restrict__ b_other,
    const bf16* __restrict__ WtKc, const float* __restrict__ b_k,
    const bf16* __restrict__ WtVc,
    float* __restrict__ att_out, bf16* __restrict__ hb)
{
  __shared__ bf16 ldsO[80 * 264];     // 42240 B  other_em (16B-group stride 33)
  __shared__ bf16 ldsA1[80 * 40];     //  6400 B  agents tile; REUSED: spart/attl
  __shared__ bf16 qh16[1024];         //  2048 B  q (bf16); REUSED: h partials
  __shared__ bf16 svl16[1024];        //  2048 B  sv (bf16)
  float* spart = (float*)ldsA1;        // [0..320)  floats: 4 K-waves x 80 rows
  float* attl  = (float*)ldsA1 + 320;  // [320..400) floats: att weights, row order

  const int tid = threadIdx.x, wave = tid >> 6, lane = tid & 63;
  const int quad = lane >> 4, m = lane & 15;
  const int b0 = blockIdx.x * 4;
  const int kvw = wave & 3;            // column-group within K or V half
  const bool isV = wave >= 4;

  // ---- phase 0: stage q, sv (bf16 copies), agents_info (interleaved rows)
  ((unsigned*)qh16)[tid]  = ((const unsigned*)(qb  + (size_t)b0 * 256))[tid];
  ((unsigned*)svl16)[tid] = ((const unsigned*)(svb + (size_t)b0 * 256))[tid];
  for (int i = tid; i < 80 * 16; i += 512) {
    int r = i >> 4, kk = (i & 15) * 2;   // lds row r = agent*4 + batch
    int n = r >> 2, bb = r & 3;
    float v0 = 0.f, v1 = 0.f;
    if (n < 19) {
      const float* base = x + (size_t)(b0 + bb) * NOBS + 36 + n * 28;
      if (kk < 28) v0 = base[kk];
      if (kk + 1 < 28) v1 = base[kk + 1];
    }
    unsigned u0 = bfbits(v0), u1 = bfbits(v1);
    *(unsigned*)(ldsA1 + r * 40 + kk) = u0 | (u1 << 16);
  }

  const f32x4 z4 = {0.f, 0.f, 0.f, 0.f};

  // ---- issue first main-loop B buffer early (independent of all LDS)
  const bf16* __restrict__ Bc = isV ? WtVc : WtKc;
  const int cb = (kvw * 64 + m) * 32 + quad * 8;   // ((4*kvw+c)*16+m)*32+q*8 == cb+c*512
  bf16x8 bE[4];
#pragma unroll
  for (int c = 0; c < 4; ++c) bE[c] = *(const bf16x8*)(Bc + cb + c * 512);

  __syncthreads();

  // ---- phase 1: other_em = relu(A1 @ WtOther^T + b_other), K=32.
  {
    float bo[2];
    bf16x8 bfr[2];
#pragma unroll
    for (int c = 0; c < 2; ++c) {
      int col = (2 * wave + c) * 16 + m;
      bo[c] = b_other[col];
      bfr[c] = *(const bf16x8*)(WtOther + col * 32 + quad * 8);
    }
    f32x4 acc1[5][2];
#pragma unroll
    for (int rt = 0; rt < 5; ++rt) {
      bf16x8 a = *(const bf16x8*)(ldsA1 + (rt * 16 + m) * 40 + quad * 8);
#pragma unroll
      for (int c = 0; c < 2; ++c)
        acc1[rt][c] = __builtin_amdgcn_mfma_f32_16x16x32_bf16(a, bfr[c], z4, 0, 0, 0);
    }
    // direct b16 stores: every lane writes its own column (bit-identical
    // values; adjacent m-lanes share a dword -> 2 lanes/bank, free)
#pragma unroll
    for (int rt = 0; rt < 5; ++rt)
#pragma unroll
      for (int c = 0; c < 2; ++c) {
        int col = (2 * wave + c) * 16 + m;
#pragma unroll
        for (int r = 0; r < 4; ++r) {
          float v = acc1[rt][c][r] + bo[c];
          v = v > 0.f ? v : 0.f;
          int rowl = rt * 16 + quad * 4 + r;
          ldsO[rowl * 264 + col] = (bf16)v;
        }
      }
  }
  __syncthreads();   // ldsA1 (agents tile) dead from here; spart/attl overlay

  // ---- unified main GEMM: 80 rows x 512 cols ([WtK | WtV]), 8 chunks,
  // ping-pong software pipeline (prefetch distance 1, no conditionals).
  f32x4 acc[5][4];
#pragma unroll
  for (int rt = 0; rt < 5; ++rt)
#pragma unroll
    for (int c = 0; c < 4; ++c) acc[rt][c] = z4;

  {
#pragma unroll 1
    for (int ch = 0; ch < 8; ch += 2) {
      bf16x8 bO[4];
#pragma unroll
      for (int c = 0; c < 4; ++c)
        bO[c] = *(const bf16x8*)(Bc + (size_t)(ch + 1) * 8192 + cb + c * 512);
      const int kc0 = ch * 32;
#pragma unroll
      for (int rt = 0; rt < 5; ++rt) {
        bf16x8 a = *(const bf16x8*)(ldsO + (rt * 16 + m) * 264 + kc0 + quad * 8);
#pragma unroll
        for (int c = 0; c < 4; ++c)
          acc[rt][c] = __builtin_amdgcn_mfma_f32_16x16x32_bf16(a, bE[c], acc[rt][c], 0, 0, 0);
      }
      // prefetch ch+2; at ch==6 this reads chunk 8 = adjacent weight region
#pragma unroll
      for (int c = 0; c < 4; ++c)
        bE[c] = *(const bf16x8*)(Bc + (size_t)(ch + 2) * 8192 + cb + c * 512);
      const int kc1 = kc0 + 32;
#pragma unroll
      for (int rt = 0; rt < 5; ++rt) {
        bf16x8 a = *(const bf16x8*)(ldsO + (rt * 16 + m) * 264 + kc1 + quad * 8);
#pragma unroll
        for (int c = 0; c < 4; ++c)
          acc[rt][c] = __builtin_amdgcn_mfma_f32_16x16x32_bf16(a, bO[c], acc[rt][c], 0, 0, 0);
      }
    }
  }

  // ---- K-waves: scores = (relu(k)+b_k) . q, reduce over lanes -> spart
  if (!isV) {
    float qreg[4][4], bkreg[4];
#pragma unroll
    for (int c = 0; c < 4; ++c) {
      int col = (4 * wave + c) * 16 + m;
      bkreg[c] = b_k[col];
#pragma unroll
      for (int r = 0; r < 4; ++r) qreg[c][r] = (float)qh16[r * 256 + col];
    }
#pragma unroll
    for (int rt = 0; rt < 5; ++rt) {
      float part[4] = {0.f, 0.f, 0.f, 0.f};
#pragma unroll
      for (int c = 0; c < 4; ++c) {
#pragma unroll
        for (int r = 0; r < 4; ++r) {
          float kv = acc[rt][c][r] + bkreg[c];
          kv = kv > 0.f ? kv : 0.f;
          part[r] += kv * qreg[c][r];
        }
      }
#pragma unroll
      for (int r = 0; r < 4; ++r) {
        float p = part[r];
        p += __shfl_xor(p, 1, 64);
        p += __shfl_xor(p, 2, 64);
        p += __shfl_xor(p, 4, 64);
        p += __shfl_xor(p, 8, 64);
        if (m == 0) spart[wave * 80 + rt * 16 + quad * 4 + r] = p;
      }
    }
  }
  __syncthreads();

  // ---- softmax: wave w = batch w, lanes 0-18 = agents (width-32 tree)
  if (!isV && lane < 32) {
    const int bb = wave, j = lane;      // batch, agent
    float s = -1e30f;
    if (j < 19) {
      int row = j * 4 + bb;             // interleaved: row = agent*4 + batch
      s = (spart[row] + spart[80 + row] + spart[160 + row] + spart[240 + row]) * 0.0625f;
    }
    float mx = s;
#pragma unroll
    for (int off = 16; off >= 1; off >>= 1) mx = fmaxf(mx, __shfl_xor(mx, off, 32));
    float e = (j < 19) ? __expf(s - mx) : 0.f;
    float sum = e;
#pragma unroll
    for (int off = 16; off >= 1; off >>= 1) sum += __shfl_xor(sum, off, 32);
    float inv = 1.f / sum;
    float a = e * inv;
    if (j < 20) attl[j * 4 + bb] = a;   // j==19 writes the zero pad row
    if (j < 19) att_out[(size_t)(b0 + bb) * 19 + j] = a;
  }
  __syncthreads();

  // ---- V-waves: epilogue  h = sum_rows att * relu(v + sv)
  if (isV) {
    float svreg[4][4];
#pragma unroll
    for (int c = 0; c < 4; ++c) {
      int col = (4 * kvw + c) * 16 + m;
#pragma unroll
      for (int r = 0; r < 4; ++r) svreg[c][r] = (float)svl16[r * 256 + col];
    }
    float hacc[4][4];   // [c][batch==r]
#pragma unroll
    for (int c = 0; c < 4; ++c)
#pragma unroll
      for (int r = 0; r < 4; ++r) hacc[c][r] = 0.f;
#pragma unroll
    for (int rt = 0; rt < 5; ++rt) {
      float av[4];
#pragma unroll
      for (int r = 0; r < 4; ++r) av[r] = attl[rt * 16 + quad * 4 + r];
#pragma unroll
      for (int c = 0; c < 4; ++c) {
#pragma unroll
        for (int r = 0; r < 4; ++r) {
          float v = acc[rt][c][r] + svreg[c][r];
          v = v > 0.f ? v : 0.f;
          hacc[c][r] += v * av[r];
        }
      }
    }
#pragma unroll
    for (int c = 0; c < 4; ++c)
#pragma unroll
      for (int r = 0; r < 4; ++r) {
        float h = hacc[c][r];
        h += __shfl_xor(h, 16, 64);
        h += __shfl_xor(h, 32, 64);
        if (quad == 0) qh16[r * 256 + (4 * kvw + c) * 16 + m] = (bf16)h;
      }
  }
  __syncthreads();
  ((unsigned*)(hb + (size_t)b0 * 256))[tid] = ((const unsigned*)qh16)[tid];
}

// ---------------------------------------------------------------------------
extern "C" void kernel_launch(void* const* d_in, const int* in_sizes, int n_in,
                              void* d_out, int out_size, void* d_ws, size_t ws_size,
                              hipStream_t stream) {
  (void)in_sizes; (void)n_in; (void)out_size; (void)ws_size;
  const float* x      = (const float*)d_in[0];
  const float* eps    = (const float*)d_in[1];
  const float* W_mu   = (const float*)d_in[2];
  const float* b_mu   = (const float*)d_in[3];
  const float* W_var  = (const float*)d_in[4];
  const float* b_var  = (const float*)d_in[5];
  const float* W_self = (const float*)d_in[6];
  const float* b_self = (const float*)d_in[7];
  const float* W_other= (const float*)d_in[8];
  const float* b_other= (const float*)d_in[9];
  const float* W_q    = (const float*)d_in[10];
  const float* b_q    = (const float*)d_in[11];
  const float* W_k    = (const float*)d_in[12];
  const float* b_k    = (const float*)d_in[13];
  const float* W_v    = (const float*)d_in[14];
  const float* b_v    = (const float*)d_in[15];
  const float* W_a    = (const float*)d_in[16];
  const float* b_a    = (const float*)d_in[17];

  char* wsb = (char*)d_ws;
  bf16* WtMu    = (bf16*)(wsb + OFF_WT_MU);
  bf16* WtVar   = (bf16*)(wsb + OFF_WT_VAR);
  bf16* WtSelf  = (bf16*)(wsb + OFF_WT_SELF);
  bf16* WtOther = (bf16*)(wsb + OFF_WT_OTHER);
  bf16* WtQ     = (bf16*)(wsb + OFF_WT_Q);
  bf16* WtK     = (bf16*)(wsb + OFF_WT_K);
  bf16* WtV1    = (bf16*)(wsb + OFF_WT_V1);
  bf16* WtV2    = (bf16*)(wsb + OFF_WT_V2);
  bf16* WtA1    = (bf16*)(wsb + OFF_WT_A1);
  bf16* WtA2    = (bf16*)(wsb + OFF_WT_A2);
  bf16* zbuf    = (bf16*)(wsb + OFF_Z);
  bf16* selfbuf = (bf16*)(wsb + OFF_SELF);
  bf16* qbuf    = (bf16*)(wsb + OFF_Q);
  bf16* svbuf   = (bf16*)(wsb + OFF_SV);
  bf16* hbuf    = (bf16*)(wsb + OFF_H);

  float* out = (float*)d_out;
  float* att_out = out + (size_t)NB * 256;

  dim3 blk(256);
  wprep<<<dim3(160, 10), blk, 0, stream>>>(W_mu, W_var, W_self, W_other, W_q, W_k, W_v, W_a, wsb);
  // z = eps*exp(0.5*logvar)+mu  AND  self_em = relu(x@W_self+b), async-B staged
  gemm_zself<<<dim3(NB / 64, 4), blk, 0, stream>>>(x, WtMu, WtVar, WtSelf,
                                                   b_mu, b_var, b_self, eps, zbuf, selfbuf);
  // q = relu(z@W_q+b_q)  AND  sv = self_em@W_v[256:]+b_v, one launch (async)
  gemm_qsv<<<dim3(NB / 64, 4), blk, 0, stream>>>(zbuf, selfbuf, WtQ, WtV2,
                                                 b_q, b_v, qbuf, svbuf);
  // fused: other_em -> [k | v] unified GEMM -> scores -> softmax -> h
  k_fused<<<NB / 4, dim3(512), 0, stream>>>(x, qbuf, svbuf, WtOther, b_other, WtK, b_k,
                                            WtV1, att_out, hbuf);
  // out = relu([h; self_em] @ W_a + b_a)   (dual-A, 64x64 tiles)
  gemm_dualA<<<dim3(NB / 64, 4), blk, 0, stream>>>(hbuf, selfbuf, WtA1, WtA2, b_a, out);
}